// Round 12
// baseline (644.829 us; speedup 1.0000x reference)
//
#include <hip/hip_runtime.h>
#include <hip/hip_bf16.h>
#include <math.h>

#define NN 100000
#define NR 8
#define NE 1600000
// ED=RD=64, H=4, A=16, D1=32, D2=16

typedef __attribute__((ext_vector_type(8))) short short8v;
typedef __attribute__((ext_vector_type(4))) float float4v;
typedef __attribute__((ext_vector_type(2))) float float2v;

__device__ inline float bf2f(unsigned short u) {
  union { unsigned int i; float f; } v; v.i = ((unsigned int)u) << 16; return v.f;
}
__device__ inline unsigned short f2bf(float f) {
  __hip_bfloat16 h = __float2bfloat16(f);
  return *reinterpret_cast<unsigned short*>(&h);
}
__device__ inline float fast_tanh(float x) {
  float ex = __expf(2.f * x);
  return 1.f - 2.f * __builtin_amdgcn_rcpf(ex + 1.f);
}

// ---------------- weight prep: Wbf[c][e] bf16 col-major, rea[512] ----------------
__global__ void k_prep(const float* __restrict__ W_R, const float* __restrict__ W_A,
                       const float* __restrict__ rel, unsigned short* __restrict__ Wbf,
                       float* __restrict__ r_emb_a) {
  int tid = blockIdx.x * 256 + threadIdx.x;
  if (tid < NR * 64 * 64) {
    int r = tid >> 12;
    int i = (tid >> 6) & 63;   // embed dim e
    int k = tid & 63;          // output dim within relation
    float acc = 0.f;
    const float* wr = W_R + (r * 64 + i) * 64;
    for (int j = 0; j < 64; ++j) acc += wr[j] * W_A[j * 64 + k];
    Wbf[(r * 64 + k) * 64 + i] = f2bf(acc);   // col-major: [c=r*64+k][e=i]
  } else if (tid < NR * 64 * 64 + NR * 64) {
    int idx = tid - NR * 64 * 64;
    int r = idx >> 6, k = idx & 63;
    float acc = 0.f;
    for (int j = 0; j < 64; ++j) acc += rel[r * 64 + j] * W_A[j * 64 + k];
    r_emb_a[idx] = acc;
  }
}

// ---------------- entity -> bf16 copy ----------------
__global__ void k_cvt(const float* __restrict__ E, unsigned short* __restrict__ Ebf) {
  int i = blockIdx.x * 256 + threadIdx.x;  // handles 4 floats
  float4 v = ((const float4*)E)[i];
  ushort4 o;
  o.x = f2bf(v.x); o.y = f2bf(v.y); o.z = f2bf(v.z); o.w = f2bf(v.w);
  ((ushort4*)Ebf)[i] = o;
}

// ---------------- proj via MFMA, node-major fp8 output with packed dword stores ---
__global__ void k_proj(const unsigned short* __restrict__ Ebf,
                       const unsigned short* __restrict__ Wbf,
                       const float* __restrict__ rea,
                       unsigned char* __restrict__ T1n, unsigned char* __restrict__ T2n) {
  int wv = threadIdx.x >> 6, lane = threadIdx.x & 63;
  int n0 = blockIdx.x * 64 + wv * 16;
  int mrow = lane & 15, kg = lane >> 4;  // kg in 0..3
  int node = n0 + mrow;
  int nodeC = (node < NN) ? node : NN - 1;
  bool ok = (node < NN);
  const short8v b0 = *(const short8v*)(Ebf + (long)nodeC * 64 + kg * 8);
  const short8v b1 = *(const short8v*)(Ebf + (long)nodeC * 64 + 32 + kg * 8);
  for (int ct = 0; ct < 32; ++ct) {
    int ca = ct * 16 + mrow;  // A-row (c) this lane loads
    const short8v a0 = *(const short8v*)(Wbf + ca * 64 + kg * 8);
    const short8v a1 = *(const short8v*)(Wbf + ca * 64 + 32 + kg * 8);
    float4v acc = {0.f, 0.f, 0.f, 0.f};
    acc = __builtin_amdgcn_mfma_f32_16x16x32_bf16(a0, b0, acc, 0, 0, 0);
    acc = __builtin_amdgcn_mfma_f32_16x16x32_bf16(a1, b1, acc, 0, 0, 0);
    int c0 = ct * 16 + kg * 4;  // this lane's 4 consecutive output cols
    float4 rv4 = *(const float4*)(rea + c0);
    unsigned int p1 = __builtin_amdgcn_cvt_pk_fp8_f32(fast_tanh(acc[0]), fast_tanh(acc[1]), 0u, false);
    p1 = __builtin_amdgcn_cvt_pk_fp8_f32(fast_tanh(acc[2]), fast_tanh(acc[3]), p1, true);
    unsigned int p2 = __builtin_amdgcn_cvt_pk_fp8_f32(fast_tanh(acc[0] + rv4.x), fast_tanh(acc[1] + rv4.y), 0u, false);
    p2 = __builtin_amdgcn_cvt_pk_fp8_f32(fast_tanh(acc[2] + rv4.z), fast_tanh(acc[3] + rv4.w), p2, true);
    if (ok) {
      *(unsigned int*)(T1n + (long)node * 512 + c0) = p1;
      *(unsigned int*)(T2n + (long)node * 512 + c0) = p2;
    }
  }
}

// ---------------- CSR build ----------------
// hist also records each edge's position within its destination's run.
__global__ void k_hist(const int* __restrict__ dst, int* __restrict__ cnt,
                       int* __restrict__ epos) {
  int e = blockIdx.x * 256 + threadIdx.x;
  if (e < NE) epos[e] = atomicAdd(&cnt[dst[e]], 1);
}

#define SCAN_B 1024
#define NSCAN ((NN + SCAN_B - 1) / SCAN_B)  // 98

__global__ void k_scan1(const int* __restrict__ cnt, int* __restrict__ rowp,
                        int* __restrict__ bsum) {
  __shared__ int s[SCAN_B];
  int t = threadIdx.x, g = blockIdx.x * SCAN_B + t;
  s[t] = (g < NN) ? cnt[g] : 0;
  __syncthreads();
  for (int off = 1; off < SCAN_B; off <<= 1) {
    int x = (t >= off) ? s[t - off] : 0;
    __syncthreads();
    s[t] += x;
    __syncthreads();
  }
  if (g < NN) rowp[g + 1] = s[t];
  if (t == SCAN_B - 1) bsum[blockIdx.x] = s[t];
}

__global__ void k_scan2(int* bsum) {
  if (threadIdx.x == 0) {
    int acc = 0;
    for (int i = 0; i < NSCAN; ++i) { int v = bsum[i]; bsum[i] = acc; acc += v; }
  }
}

__global__ void k_scan3(int* rowp, const int* __restrict__ bsum) {
  int t = threadIdx.x, g = blockIdx.x * SCAN_B + t;
  if (g < NN) rowp[g + 1] += bsum[blockIdx.x];
  if (g == 0) rowp[0] = 0;
}

// scatter (atomic-free): p = rowp[dst] + epos; ONE packed 8-byte record per edge
__global__ void k_scatter(const int* __restrict__ src, const int* __restrict__ dst,
                          const int* __restrict__ etype, const int* __restrict__ rowp,
                          const int* __restrict__ epos, uint2* __restrict__ rec) {
  int e = blockIdx.x * 256 + threadIdx.x;
  if (e >= NE) return;
  int d = dst[e];
  int p = rowp[d] + epos[e];
  uint2 rv;
  rv.x = ((unsigned int)src[e] << 3) | (unsigned int)etype[e];
  rv.y = (unsigned int)d;
  rec[p] = rv;
}

// ---------------- fused attention + max-free softmax + message + transform, L0 ----
// wave per node; 8 edges/iter; 8 lanes/edge. Lane (g=lane>>3 slot, q=lane&7).
// Lane's T-slice bytes q*8..q*8+7 lie in head q>>1; one shfl_xor(1) completes
// the head logit. |per-head logit| <= 16 so exp() without max is f32-safe.
__global__ void k_fused0(const float* __restrict__ E, const unsigned short* __restrict__ Ebf,
                         const unsigned char* __restrict__ T1n,
                         const unsigned char* __restrict__ T2n,
                         const uint2* __restrict__ rec, const int* __restrict__ rowp,
                         float* __restrict__ att4, float* __restrict__ zinv4,
                         const float* __restrict__ W1, const float* __restrict__ b1,
                         const float* __restrict__ W2, const float* __restrict__ b2,
                         float* __restrict__ ego1, unsigned short* __restrict__ ego1bf) {
  __shared__ float wt1[8][68], wt2[8][68];  // transposed weights [j][d]
  __shared__ float bb[16];
  __shared__ float s1[4][4][68], s2[4][4][68];
  int t = threadIdx.x;
  for (int i = t; i < 512; i += 256) {
    int d = i >> 3, j = i & 7;
    wt1[j][d] = W1[i];
    wt2[j][d] = W2[i];
  }
  if (t < 8) bb[t] = b1[t];
  else if (t < 16) bb[t] = b2[t - 8];
  __syncthreads();
  int wv = t >> 6, lane = t & 63;
  int n = blockIdx.x * 4 + wv;
  int p0 = rowp[n], p1 = rowp[n + 1];
  int g = lane >> 3, q = lane & 7;
  int gbase = lane & 56;
  const unsigned int* recw = (const unsigned int*)rec;
  float acc[4][8];  // [head][dim within octet]
#pragma unroll
  for (int h = 0; h < 4; ++h)
#pragma unroll
    for (int j = 0; j < 8; ++j) acc[h][j] = 0.f;
  float z0 = 0.f, z1 = 0.f, z2 = 0.f, z3 = 0.f;
  for (int p = p0 + g; p < p1; p += 8) {
    unsigned int rv = recw[p * 2];
    int s = (int)(rv >> 3), r = (int)(rv & 7);
    uint2 aw = *(const uint2*)(T1n + (long)s * 512 + r * 64 + q * 8);
    uint2 bw = *(const uint2*)(T2n + (long)n * 512 + r * 64 + q * 8);
    float2v a0 = __builtin_amdgcn_cvt_pk_f32_fp8(aw.x, false);
    float2v a1 = __builtin_amdgcn_cvt_pk_f32_fp8(aw.x, true);
    float2v a2 = __builtin_amdgcn_cvt_pk_f32_fp8(aw.y, false);
    float2v a3 = __builtin_amdgcn_cvt_pk_f32_fp8(aw.y, true);
    float2v c0 = __builtin_amdgcn_cvt_pk_f32_fp8(bw.x, false);
    float2v c1 = __builtin_amdgcn_cvt_pk_f32_fp8(bw.x, true);
    float2v c2 = __builtin_amdgcn_cvt_pk_f32_fp8(bw.y, false);
    float2v c3 = __builtin_amdgcn_cvt_pk_f32_fp8(bw.y, true);
    float dot = a0.x * c0.x + a0.y * c0.y + a1.x * c1.x + a1.y * c1.y
              + a2.x * c2.x + a2.y * c2.y + a3.x * c3.x + a3.y * c3.y;
    dot += __shfl_xor(dot, 1);       // lanes 2h,2h+1 of group hold head-h logit
    float e = __expf(dot);           // max-free: |logit| <= 16
    float e0 = __shfl(e, gbase + 0);
    float e1 = __shfl(e, gbase + 2);
    float e2 = __shfl(e, gbase + 4);
    float e3 = __shfl(e, gbase + 6);
    z0 += e0; z1 += e1; z2 += e2; z3 += e3;
    if (q == 0) ((float4*)att4)[p] = make_float4(e0, e1, e2, e3);
    short8v ev8 = *(const short8v*)(Ebf + (long)s * 64 + q * 8);
#pragma unroll
    for (int j = 0; j < 8; ++j) {
      float v = bf2f((unsigned short)ev8[j]);
      acc[0][j] += e0 * v;
      acc[1][j] += e1 * v;
      acc[2][j] += e2 * v;
      acc[3][j] += e3 * v;
    }
  }
#pragma unroll
  for (int h = 0; h < 4; ++h)
#pragma unroll
    for (int j = 0; j < 8; ++j) {
      acc[h][j] += __shfl_xor(acc[h][j], 8);
      acc[h][j] += __shfl_xor(acc[h][j], 16);
      acc[h][j] += __shfl_xor(acc[h][j], 32);
    }
  z0 += __shfl_xor(z0, 8); z0 += __shfl_xor(z0, 16); z0 += __shfl_xor(z0, 32);
  z1 += __shfl_xor(z1, 8); z1 += __shfl_xor(z1, 16); z1 += __shfl_xor(z1, 32);
  z2 += __shfl_xor(z2, 8); z2 += __shfl_xor(z2, 16); z2 += __shfl_xor(z2, 32);
  z3 += __shfl_xor(z3, 8); z3 += __shfl_xor(z3, 16); z3 += __shfl_xor(z3, 32);
  float zi0 = 1.f / fmaxf(z0, 1e-12f);
  float zi1 = 1.f / fmaxf(z1, 1e-12f);
  float zi2 = 1.f / fmaxf(z2, 1e-12f);
  float zi3 = 1.f / fmaxf(z3, 1e-12f);
  if (lane == 0) *(float4*)(zinv4 + n * 4) = make_float4(zi0, zi1, zi2, zi3);
  if (lane < 8) {
    float zi[4] = {zi0, zi1, zi2, zi3};
    float4 eda = *(const float4*)(E + n * 64 + q * 8);
    float4 edb = *(const float4*)(E + n * 64 + q * 8 + 4);
#pragma unroll
    for (int h = 0; h < 4; ++h) {
      float4 v1a, v2a, v1b, v2b;
      float m0 = acc[h][0] * zi[h], m1 = acc[h][1] * zi[h];
      float m2 = acc[h][2] * zi[h], m3 = acc[h][3] * zi[h];
      float m4 = acc[h][4] * zi[h], m5 = acc[h][5] * zi[h];
      float m6 = acc[h][6] * zi[h], m7 = acc[h][7] * zi[h];
      v1a.x = eda.x + m0; v2a.x = eda.x * m0;
      v1a.y = eda.y + m1; v2a.y = eda.y * m1;
      v1a.z = eda.z + m2; v2a.z = eda.z * m2;
      v1a.w = eda.w + m3; v2a.w = eda.w * m3;
      v1b.x = edb.x + m4; v2b.x = edb.x * m4;
      v1b.y = edb.y + m5; v2b.y = edb.y * m5;
      v1b.z = edb.z + m6; v2b.z = edb.z * m6;
      v1b.w = edb.w + m7; v2b.w = edb.w * m7;
      *(float4*)&s1[wv][h][q * 8] = v1a;
      *(float4*)&s1[wv][h][q * 8 + 4] = v1b;
      *(float4*)&s2[wv][h][q * 8] = v2a;
      *(float4*)&s2[wv][h][q * 8 + 4] = v2b;
    }
  }
  __syncthreads();
  int h = (lane >> 3) & 3, j = lane & 7;
  const float* sp = (lane < 32) ? &s1[wv][h][0] : &s2[wv][h][0];
  const float* wp = (lane < 32) ? &wt1[j][0] : &wt2[j][0];
  float o = 0.f;
#pragma unroll
  for (int d = 0; d < 64; d += 4) {
    float4 sv = *(const float4*)(sp + d);
    float4 wv4 = *(const float4*)(wp + d);
    o += sv.x * wv4.x + sv.y * wv4.y + sv.z * wv4.z + sv.w * wv4.w;
  }
  o += (lane < 32) ? bb[j] : bb[8 + j];
  o = (o >= 0.f) ? o : 0.01f * o;
  float other = __shfl_xor(o, 32);
  if (lane < 32) {
    float r = o + other;
    ego1[n * 32 + h * 8 + j] = r;
    ego1bf[n * 32 + h * 8 + j] = f2bf(r);
  }
}

// ---------------- fused message + bi-transform, layer 1 ----------------
// wave per node; 16 edges/iter; 4 lanes/edge (q=lane&3, dims q*8..q*8+7).
__global__ void k_fused1(const float* __restrict__ ego1, const unsigned short* __restrict__ E1bf,
                         const float* __restrict__ att4, const float* __restrict__ zinv4,
                         const uint2* __restrict__ rec, const int* __restrict__ rowp,
                         const float* __restrict__ W1, const float* __restrict__ b1,
                         const float* __restrict__ W2, const float* __restrict__ b2,
                         float* __restrict__ ego2) {
  __shared__ float wt1[4][36], wt2[4][36], bb[8];
  __shared__ float s1[4][4][36], s2[4][4][36];
  int t = threadIdx.x;
  if (t < 128) { int d = t >> 2, j = t & 3; wt1[j][d] = W1[t]; wt2[j][d] = W2[t]; }
  if (t < 4) bb[t] = b1[t];
  else if (t < 8) bb[t] = b2[t - 4];
  __syncthreads();
  int wv = t >> 6, lane = t & 63;
  int n = blockIdx.x * 4 + wv;
  int p0 = rowp[n], p1 = rowp[n + 1];
  int g = lane >> 2, q = lane & 3;
  const unsigned int* recw = (const unsigned int*)rec;
  float acc[4][8];
#pragma unroll
  for (int h = 0; h < 4; ++h)
#pragma unroll
    for (int j = 0; j < 8; ++j) acc[h][j] = 0.f;
  for (int p = p0 + g; p < p1; p += 16) {
    int s = (int)(recw[p * 2] >> 3);
    float4 a = ((const float4*)att4)[p];
    short8v ev8 = *(const short8v*)(E1bf + (long)s * 32 + q * 8);
#pragma unroll
    for (int j = 0; j < 8; ++j) {
      float v = bf2f((unsigned short)ev8[j]);
      acc[0][j] += a.x * v;
      acc[1][j] += a.y * v;
      acc[2][j] += a.z * v;
      acc[3][j] += a.w * v;
    }
  }
#pragma unroll
  for (int h = 0; h < 4; ++h)
#pragma unroll
    for (int j = 0; j < 8; ++j) {
      acc[h][j] += __shfl_xor(acc[h][j], 4);
      acc[h][j] += __shfl_xor(acc[h][j], 8);
      acc[h][j] += __shfl_xor(acc[h][j], 16);
      acc[h][j] += __shfl_xor(acc[h][j], 32);
    }
  if (lane < 4) {
    float4 zi = *(const float4*)(zinv4 + n * 4);
    float zih[4] = {zi.x, zi.y, zi.z, zi.w};
    float4 e1a = *(const float4*)(ego1 + n * 32 + q * 8);
    float4 e1b = *(const float4*)(ego1 + n * 32 + q * 8 + 4);
#pragma unroll
    for (int h = 0; h < 4; ++h) {
      float m0 = acc[h][0] * zih[h], m1 = acc[h][1] * zih[h];
      float m2 = acc[h][2] * zih[h], m3 = acc[h][3] * zih[h];
      float m4 = acc[h][4] * zih[h], m5 = acc[h][5] * zih[h];
      float m6 = acc[h][6] * zih[h], m7 = acc[h][7] * zih[h];
      float4 v1a, v2a, v1b, v2b;
      v1a.x = e1a.x + m0; v2a.x = e1a.x * m0;
      v1a.y = e1a.y + m1; v2a.y = e1a.y * m1;
      v1a.z = e1a.z + m2; v2a.z = e1a.z * m2;
      v1a.w = e1a.w + m3; v2a.w = e1a.w * m3;
      v1b.x = e1b.x + m4; v2b.x = e1b.x * m4;
      v1b.y = e1b.y + m5; v2b.y = e1b.y * m5;
      v1b.z = e1b.z + m6; v2b.z = e1b.z * m6;
      v1b.w = e1b.w + m7; v2b.w = e1b.w * m7;
      *(float4*)&s1[wv][h][q * 8] = v1a;
      *(float4*)&s1[wv][h][q * 8 + 4] = v1b;
      *(float4*)&s2[wv][h][q * 8] = v2a;
      *(float4*)&s2[wv][h][q * 8 + 4] = v2b;
    }
  }
  __syncthreads();
  if (lane < 32) {
    int h = (lane >> 2) & 3, j = lane & 3;
    const float* sp = (lane < 16) ? &s1[wv][h][0] : &s2[wv][h][0];
    const float* wp = (lane < 16) ? &wt1[j][0] : &wt2[j][0];
    float o = 0.f;
#pragma unroll
    for (int dd = 0; dd < 32; dd += 4) {
      float4 sv = *(const float4*)(sp + dd);
      float4 wv4 = *(const float4*)(wp + dd);
      o += sv.x * wv4.x + sv.y * wv4.y + sv.z * wv4.z + sv.w * wv4.w;
    }
    o += (lane < 16) ? bb[j] : bb[4 + j];
    o = (o >= 0.f) ? o : 0.01f * o;
    float other = __shfl_xor(o, 16);
    if (lane < 16) ego2[n * 16 + h * 4 + j] = o + other;
  }
}

// ---------------- gather user/item rows with l2norm into U, V ----------------
__global__ void k_uv(const float* __restrict__ E, const float* __restrict__ E1,
                     const float* __restrict__ E2, const int* __restrict__ uid,
                     const int* __restrict__ iid, float* __restrict__ U,
                     float* __restrict__ V) {
  int row = (blockIdx.x * 256 + threadIdx.x) >> 6;
  int lane = threadIdx.x & 63;
  if (row >= 1000 + 4096) return;
  int id = (row < 1000) ? uid[row] : iid[row - 1000];
  float* dest = (row < 1000) ? (U + row * 112) : (V + (row - 1000) * 112);
  float v1 = (lane < 32) ? E1[id * 32 + lane] : 0.f;
  float s1 = v1 * v1;
  for (int m = 1; m < 64; m <<= 1) s1 += __shfl_xor(s1, m);
  float v2 = (lane < 16) ? E2[id * 16 + lane] : 0.f;
  float s2 = v2 * v2;
  for (int m = 1; m < 64; m <<= 1) s2 += __shfl_xor(s2, m);
  float i1 = 1.f / fmaxf(sqrtf(s1), 1e-12f);
  float i2 = 1.f / fmaxf(sqrtf(s2), 1e-12f);
  dest[lane] = E[id * 64 + lane];
  if (lane < 32) dest[64 + lane] = v1 * i1;
  if (lane < 16) dest[96 + lane] = v2 * i2;
}

// ---------------- final small GEMM: C[1000,4096] = U @ V^T (K=112) ----------------
__global__ void k_gemm(const float* __restrict__ U, const float* __restrict__ V,
                       float* __restrict__ C) {
  __shared__ float Us[16][113], Vs[16][113];
  int tx = threadIdx.x & 15, ty = threadIdx.x >> 4;
  int u0 = blockIdx.y * 16, v0 = blockIdx.x * 16;
  for (int i = threadIdx.x; i < 16 * 112; i += 256) {
    int rr = i / 112, cc = i % 112;
    int ur = u0 + rr;
    Us[rr][cc] = (ur < 1000) ? U[ur * 112 + cc] : 0.f;
    Vs[rr][cc] = V[(v0 + rr) * 112 + cc];
  }
  __syncthreads();
  int u = u0 + ty;
  if (u >= 1000) return;
  float acc = 0.f;
#pragma unroll
  for (int k = 0; k < 112; ++k) acc += Us[ty][k] * Vs[tx][k];
  C[u * 4096 + v0 + tx] = acc;
}

extern "C" void kernel_launch(void* const* d_in, const int* in_sizes, int n_in,
                              void* d_out, int out_size, void* d_ws, size_t ws_size,
                              hipStream_t stream) {
  const int* src = (const int*)d_in[0];
  const int* dst = (const int*)d_in[1];
  const int* etype = (const int*)d_in[2];
  const int* uid = (const int*)d_in[4];
  const int* iid = (const int*)d_in[5];
  const float* entity = (const float*)d_in[6];
  const float* rel = (const float*)d_in[7];
  const float* W_R = (const float*)d_in[8];
  const float* W_A = (const float*)d_in[9];
  const float* W1_0 = (const float*)d_in[10];
  const float* b1_0 = (const float*)d_in[11];
  const float* W2_0 = (const float*)d_in[12];
  const float* b2_0 = (const float*)d_in[13];
  const float* W1_1 = (const float*)d_in[14];
  const float* b1_1 = (const float*)d_in[15];
  const float* W2_1 = (const float*)d_in[16];
  const float* b2_1 = (const float*)d_in[17];
  float* out = (float*)d_out;

  char* ws = (char*)d_ws;
  // ego1/e1bf/ego2 must NOT alias T1n/T2n (k_fused0 reads T while writing ego1).
  unsigned char*  T1n  = (unsigned char*) (ws + 0);            //  51,200,000
  unsigned char*  T2n  = (unsigned char*) (ws + 51200000);     //  51,200,000
  float*          att4 = (float*)         (ws + 102400000);    //  25,600,000 (raw e)
  uint2*          rec  = (uint2*)         (ws + 128000000);    //  12,800,000
  int*            rowp = (int*)           (ws + 140800000);    //     400,128
  int*            cnt  = (int*)           (ws + 141200128);    //     400,128
  int*            bsum = (int*)           (ws + 141600256);    //         512
  unsigned short* Wbf  = (unsigned short*)(ws + 141600768);    //      65,536
  float*          rea  = (float*)         (ws + 141666304);    //       2,048
  unsigned short* Ebf  = (unsigned short*)(ws + 141668352);    //  12,800,000
  float*          zinv4= (float*)         (ws + 154468352);    //   1,600,000
  float*          ego1 = (float*)         (ws + 156068352);    //  12,800,000
  unsigned short* e1bf = (unsigned short*)(ws + 168868352);    //   6,400,000
  float*          ego2 = (float*)         (ws + 175268352);    //   6,400,000
  float*          U    = (float*)         (ws + 181668352);    //     448,000
  float*          V    = (float*)         (ws + 182116352);    //   1,835,008
  int*            epos = (int*)           (ws + 183951360);    //   6,400,000
  // total: 190,351,360 bytes

  hipMemsetAsync(cnt, 0, NN * sizeof(int), stream);
  k_prep<<<130, 256, 0, stream>>>(W_R, W_A, rel, Wbf, rea);
  k_cvt<<<6250, 256, 0, stream>>>(entity, Ebf);
  k_proj<<<(NN + 63) / 64, 256, 0, stream>>>(Ebf, Wbf, rea, T1n, T2n);
  k_hist<<<NE / 256, 256, 0, stream>>>(dst, cnt, epos);
  k_scan1<<<NSCAN, SCAN_B, 0, stream>>>(cnt, rowp, bsum);
  k_scan2<<<1, 64, 0, stream>>>(bsum);
  k_scan3<<<NSCAN, SCAN_B, 0, stream>>>(rowp, bsum);
  k_scatter<<<NE / 256, 256, 0, stream>>>(src, dst, etype, rowp, epos, rec);
  k_fused0<<<NN / 4, 256, 0, stream>>>(entity, Ebf, T1n, T2n, rec, rowp,
                                       att4, zinv4, W1_0, b1_0, W2_0, b2_0,
                                       ego1, e1bf);
  k_fused1<<<NN / 4, 256, 0, stream>>>(ego1, e1bf, att4, zinv4, rec, rowp,
                                       W1_1, b1_1, W2_1, b2_1, ego2);
  k_uv<<<(1000 + 4096 + 3) / 4, 256, 0, stream>>>(entity, ego1, ego2, uid, iid, U, V);
  k_gemm<<<dim3(4096 / 16, (1000 + 15) / 16), 256, 0, stream>>>(U, V, out);
}

// Round 13
// 503.436 us; speedup vs baseline: 1.2809x; 1.2809x over previous
//
#include <hip/hip_runtime.h>
#include <hip/hip_bf16.h>
#include <math.h>

#define NN 100000
#define NR 8
#define NE 1600000
// ED=RD=64, H=4, A=16, D1=32, D2=16

typedef __attribute__((ext_vector_type(8))) short short8v;
typedef __attribute__((ext_vector_type(4))) float float4v;
typedef __attribute__((ext_vector_type(2))) float float2v;

__device__ inline float bf2f(unsigned short u) {
  union { unsigned int i; float f; } v; v.i = ((unsigned int)u) << 16; return v.f;
}
__device__ inline unsigned short f2bf(float f) {
  __hip_bfloat16 h = __float2bfloat16(f);
  return *reinterpret_cast<unsigned short*>(&h);
}
__device__ inline float fast_tanh(float x) {
  float ex = __expf(2.f * x);
  return 1.f - 2.f * __builtin_amdgcn_rcpf(ex + 1.f);
}

// ---------------- weight prep: Wbf[c][e] bf16 col-major, rea[512] ----------------
__global__ void k_prep(const float* __restrict__ W_R, const float* __restrict__ W_A,
                       const float* __restrict__ rel, unsigned short* __restrict__ Wbf,
                       float* __restrict__ r_emb_a) {
  int tid = blockIdx.x * 256 + threadIdx.x;
  if (tid < NR * 64 * 64) {
    int r = tid >> 12;
    int i = (tid >> 6) & 63;   // embed dim e
    int k = tid & 63;          // output dim within relation
    float acc = 0.f;
    const float* wr = W_R + (r * 64 + i) * 64;
    for (int j = 0; j < 64; ++j) acc += wr[j] * W_A[j * 64 + k];
    Wbf[(r * 64 + k) * 64 + i] = f2bf(acc);   // col-major: [c=r*64+k][e=i]
  } else if (tid < NR * 64 * 64 + NR * 64) {
    int idx = tid - NR * 64 * 64;
    int r = idx >> 6, k = idx & 63;
    float acc = 0.f;
    for (int j = 0; j < 64; ++j) acc += rel[r * 64 + j] * W_A[j * 64 + k];
    r_emb_a[idx] = acc;
  }
}

// ---------------- entity -> bf16 copy ----------------
__global__ void k_cvt(const float* __restrict__ E, unsigned short* __restrict__ Ebf) {
  int i = blockIdx.x * 256 + threadIdx.x;  // handles 4 floats
  float4 v = ((const float4*)E)[i];
  ushort4 o;
  o.x = f2bf(v.x); o.y = f2bf(v.y); o.z = f2bf(v.z); o.w = f2bf(v.w);
  ((ushort4*)Ebf)[i] = o;
}

// ---------------- proj via MFMA, node-major fp8 output with packed dword stores ---
__global__ void k_proj(const unsigned short* __restrict__ Ebf,
                       const unsigned short* __restrict__ Wbf,
                       const float* __restrict__ rea,
                       unsigned char* __restrict__ T1n, unsigned char* __restrict__ T2n) {
  int wv = threadIdx.x >> 6, lane = threadIdx.x & 63;
  int n0 = blockIdx.x * 64 + wv * 16;
  int mrow = lane & 15, kg = lane >> 4;  // kg in 0..3
  int node = n0 + mrow;
  int nodeC = (node < NN) ? node : NN - 1;
  bool ok = (node < NN);
  const short8v b0 = *(const short8v*)(Ebf + (long)nodeC * 64 + kg * 8);
  const short8v b1 = *(const short8v*)(Ebf + (long)nodeC * 64 + 32 + kg * 8);
  for (int ct = 0; ct < 32; ++ct) {
    int ca = ct * 16 + mrow;  // A-row (c) this lane loads
    const short8v a0 = *(const short8v*)(Wbf + ca * 64 + kg * 8);
    const short8v a1 = *(const short8v*)(Wbf + ca * 64 + 32 + kg * 8);
    float4v acc = {0.f, 0.f, 0.f, 0.f};
    acc = __builtin_amdgcn_mfma_f32_16x16x32_bf16(a0, b0, acc, 0, 0, 0);
    acc = __builtin_amdgcn_mfma_f32_16x16x32_bf16(a1, b1, acc, 0, 0, 0);
    int c0 = ct * 16 + kg * 4;  // this lane's 4 consecutive output cols
    float4 rv4 = *(const float4*)(rea + c0);
    unsigned int p1 = __builtin_amdgcn_cvt_pk_fp8_f32(fast_tanh(acc[0]), fast_tanh(acc[1]), 0u, false);
    p1 = __builtin_amdgcn_cvt_pk_fp8_f32(fast_tanh(acc[2]), fast_tanh(acc[3]), p1, true);
    unsigned int p2 = __builtin_amdgcn_cvt_pk_fp8_f32(fast_tanh(acc[0] + rv4.x), fast_tanh(acc[1] + rv4.y), 0u, false);
    p2 = __builtin_amdgcn_cvt_pk_fp8_f32(fast_tanh(acc[2] + rv4.z), fast_tanh(acc[3] + rv4.w), p2, true);
    if (ok) {
      *(unsigned int*)(T1n + (long)node * 512 + c0) = p1;
      *(unsigned int*)(T2n + (long)node * 512 + c0) = p2;
    }
  }
}

// ---------------- CSR build ----------------
// hist also records each edge's position within its destination's run.
__global__ void k_hist(const int* __restrict__ dst, int* __restrict__ cnt,
                       int* __restrict__ epos) {
  int e = blockIdx.x * 256 + threadIdx.x;
  if (e < NE) epos[e] = atomicAdd(&cnt[dst[e]], 1);
}

#define SCAN_B 1024
#define NSCAN ((NN + SCAN_B - 1) / SCAN_B)  // 98

__global__ void k_scan1(const int* __restrict__ cnt, int* __restrict__ rowp,
                        int* __restrict__ bsum) {
  __shared__ int s[SCAN_B];
  int t = threadIdx.x, g = blockIdx.x * SCAN_B + t;
  s[t] = (g < NN) ? cnt[g] : 0;
  __syncthreads();
  for (int off = 1; off < SCAN_B; off <<= 1) {
    int x = (t >= off) ? s[t - off] : 0;
    __syncthreads();
    s[t] += x;
    __syncthreads();
  }
  if (g < NN) rowp[g + 1] = s[t];
  if (t == SCAN_B - 1) bsum[blockIdx.x] = s[t];
}

__global__ void k_scan2(int* bsum) {
  if (threadIdx.x == 0) {
    int acc = 0;
    for (int i = 0; i < NSCAN; ++i) { int v = bsum[i]; bsum[i] = acc; acc += v; }
  }
}

__global__ void k_scan3(int* rowp, const int* __restrict__ bsum) {
  int t = threadIdx.x, g = blockIdx.x * SCAN_B + t;
  if (g < NN) rowp[g + 1] += bsum[blockIdx.x];
  if (g == 0) rowp[0] = 0;
}

// scatter (atomic-free): p = rowp[dst] + epos; ONE packed 8-byte record per edge
__global__ void k_scatter(const int* __restrict__ src, const int* __restrict__ dst,
                          const int* __restrict__ etype, const int* __restrict__ rowp,
                          const int* __restrict__ epos, uint2* __restrict__ rec) {
  int e = blockIdx.x * 256 + threadIdx.x;
  if (e >= NE) return;
  int d = dst[e];
  int p = rowp[d] + epos[e];
  uint2 rv;
  rv.x = ((unsigned int)src[e] << 3) | (unsigned int)etype[e];
  rv.y = (unsigned int)d;
  rec[p] = rv;
}

// ---------------- fused attention + max-free softmax + message + transform, L0 ----
// wave per node; 4 edges/iter; 16 lanes/edge. Lane (g=lane>>4 edge-slot, q=lane&15).
// Lane's T-slice bytes q*4..q*4+3 lie in head q>>2. |per-head logit| <= 16 so
// exp() without max subtraction is safe (softmax is shift-invariant).
__global__ void k_fused0(const float* __restrict__ E, const unsigned short* __restrict__ Ebf,
                         const unsigned char* __restrict__ T1n,
                         const unsigned char* __restrict__ T2n,
                         const uint2* __restrict__ rec, const int* __restrict__ rowp,
                         float* __restrict__ att4, float* __restrict__ zinv4,
                         const float* __restrict__ W1, const float* __restrict__ b1,
                         const float* __restrict__ W2, const float* __restrict__ b2,
                         float* __restrict__ ego1, unsigned short* __restrict__ ego1bf) {
  __shared__ float wt1[8][68], wt2[8][68];  // transposed weights [j][d]
  __shared__ float bb[16];
  __shared__ float s1[4][4][68], s2[4][4][68];
  int t = threadIdx.x;
  for (int i = t; i < 512; i += 256) {
    int d = i >> 3, j = i & 7;
    wt1[j][d] = W1[i];
    wt2[j][d] = W2[i];
  }
  if (t < 8) bb[t] = b1[t];
  else if (t < 16) bb[t] = b2[t - 8];
  __syncthreads();
  int wv = t >> 6, lane = t & 63;
  int n = blockIdx.x * 4 + wv;
  int p0 = rowp[n], p1 = rowp[n + 1];
  int g = lane >> 4, q = lane & 15;
  int bl = (lane & 48) | (lane & 3);  // lane g*16 + (q&3): head-0 source lane
  const unsigned int* recw = (const unsigned int*)rec;
  float acc[4][4];  // [head][dim within block]
#pragma unroll
  for (int h = 0; h < 4; ++h)
#pragma unroll
    for (int j = 0; j < 4; ++j) acc[h][j] = 0.f;
  float z0 = 0.f, z1 = 0.f, z2 = 0.f, z3 = 0.f;
  for (int p = p0 + g; p < p1; p += 4) {
    unsigned int rv = recw[p * 2];
    int s = (int)(rv >> 3), r = (int)(rv & 7);
    unsigned int aw = *(const unsigned int*)(T1n + (long)s * 512 + r * 64 + q * 4);
    unsigned int bw = *(const unsigned int*)(T2n + (long)n * 512 + r * 64 + q * 4);
    float2v fa0 = __builtin_amdgcn_cvt_pk_f32_fp8(aw, false);
    float2v fa1 = __builtin_amdgcn_cvt_pk_f32_fp8(aw, true);
    float2v fb0 = __builtin_amdgcn_cvt_pk_f32_fp8(bw, false);
    float2v fb1 = __builtin_amdgcn_cvt_pk_f32_fp8(bw, true);
    float dot = fa0.x * fb0.x + fa0.y * fb0.y + fa1.x * fb1.x + fa1.y * fb1.y;
    dot += __shfl_xor(dot, 1);
    dot += __shfl_xor(dot, 2);       // 4 lanes of head group q>>2 hold logit
    float e = __expf(dot);           // max-free: |logit| <= 16
    float e0 = __shfl(e, bl);
    float e1 = __shfl(e, bl + 4);
    float e2 = __shfl(e, bl + 8);
    float e3 = __shfl(e, bl + 12);
    z0 += e0; z1 += e1; z2 += e2; z3 += e3;
    if (q == 0) ((float4*)att4)[p] = make_float4(e0, e1, e2, e3);
    ushort4 ev = *(const ushort4*)(Ebf + s * 64 + q * 4);
    float v0 = bf2f(ev.x), v1 = bf2f(ev.y), v2 = bf2f(ev.z), v3 = bf2f(ev.w);
    acc[0][0] += e0 * v0; acc[0][1] += e0 * v1; acc[0][2] += e0 * v2; acc[0][3] += e0 * v3;
    acc[1][0] += e1 * v0; acc[1][1] += e1 * v1; acc[1][2] += e1 * v2; acc[1][3] += e1 * v3;
    acc[2][0] += e2 * v0; acc[2][1] += e2 * v1; acc[2][2] += e2 * v2; acc[2][3] += e2 * v3;
    acc[3][0] += e3 * v0; acc[3][1] += e3 * v1; acc[3][2] += e3 * v2; acc[3][3] += e3 * v3;
  }
#pragma unroll
  for (int h = 0; h < 4; ++h)
#pragma unroll
    for (int j = 0; j < 4; ++j) {
      acc[h][j] += __shfl_xor(acc[h][j], 16);
      acc[h][j] += __shfl_xor(acc[h][j], 32);
    }
  z0 += __shfl_xor(z0, 16); z0 += __shfl_xor(z0, 32);
  z1 += __shfl_xor(z1, 16); z1 += __shfl_xor(z1, 32);
  z2 += __shfl_xor(z2, 16); z2 += __shfl_xor(z2, 32);
  z3 += __shfl_xor(z3, 16); z3 += __shfl_xor(z3, 32);
  float zi0 = 1.f / fmaxf(z0, 1e-12f);
  float zi1 = 1.f / fmaxf(z1, 1e-12f);
  float zi2 = 1.f / fmaxf(z2, 1e-12f);
  float zi3 = 1.f / fmaxf(z3, 1e-12f);
  if (lane == 0) *(float4*)(zinv4 + n * 4) = make_float4(zi0, zi1, zi2, zi3);
  if (lane < 16) {
    acc[0][0] *= zi0; acc[0][1] *= zi0; acc[0][2] *= zi0; acc[0][3] *= zi0;
    acc[1][0] *= zi1; acc[1][1] *= zi1; acc[1][2] *= zi1; acc[1][3] *= zi1;
    acc[2][0] *= zi2; acc[2][1] *= zi2; acc[2][2] *= zi2; acc[2][3] *= zi2;
    acc[3][0] *= zi3; acc[3][1] *= zi3; acc[3][2] *= zi3; acc[3][3] *= zi3;
    float4 edv = *(const float4*)(E + n * 64 + q * 4);
#pragma unroll
    for (int h = 0; h < 4; ++h) {
      float4 v1v, v2v;
      v1v.x = edv.x + acc[h][0]; v2v.x = edv.x * acc[h][0];
      v1v.y = edv.y + acc[h][1]; v2v.y = edv.y * acc[h][1];
      v1v.z = edv.z + acc[h][2]; v2v.z = edv.z * acc[h][2];
      v1v.w = edv.w + acc[h][3]; v2v.w = edv.w * acc[h][3];
      *(float4*)&s1[wv][h][q * 4] = v1v;
      *(float4*)&s2[wv][h][q * 4] = v2v;
    }
  }
  __syncthreads();
  int h = (lane >> 3) & 3, j = lane & 7;
  const float* sp = (lane < 32) ? &s1[wv][h][0] : &s2[wv][h][0];
  const float* wp = (lane < 32) ? &wt1[j][0] : &wt2[j][0];
  float o = 0.f;
#pragma unroll
  for (int d = 0; d < 64; d += 4) {
    float4 sv = *(const float4*)(sp + d);
    float4 wv4 = *(const float4*)(wp + d);
    o += sv.x * wv4.x + sv.y * wv4.y + sv.z * wv4.z + sv.w * wv4.w;
  }
  o += (lane < 32) ? bb[j] : bb[8 + j];
  o = (o >= 0.f) ? o : 0.01f * o;
  float other = __shfl_xor(o, 32);
  if (lane < 32) {
    float r = o + other;
    ego1[n * 32 + h * 8 + j] = r;
    ego1bf[n * 32 + h * 8 + j] = f2bf(r);
  }
}

// ---------------- fused message + bi-transform, layer 1 ----------------
// wave per node; 8 edges/iter; raw e from att4, per-node zinv applied post-reduce.
__global__ void k_fused1(const float* __restrict__ ego1, const unsigned short* __restrict__ E1bf,
                         const float* __restrict__ att4, const float* __restrict__ zinv4,
                         const uint2* __restrict__ rec, const int* __restrict__ rowp,
                         const float* __restrict__ W1, const float* __restrict__ b1,
                         const float* __restrict__ W2, const float* __restrict__ b2,
                         float* __restrict__ ego2) {
  __shared__ float wt1[4][36], wt2[4][36], bb[8];
  __shared__ float s1[4][4][36], s2[4][4][36];
  int t = threadIdx.x;
  if (t < 128) { int d = t >> 2, j = t & 3; wt1[j][d] = W1[t]; wt2[j][d] = W2[t]; }
  if (t < 4) bb[t] = b1[t];
  else if (t < 8) bb[t] = b2[t - 4];
  __syncthreads();
  int wv = t >> 6, lane = t & 63;
  int n = blockIdx.x * 4 + wv;
  int p0 = rowp[n], p1 = rowp[n + 1];
  int g = lane >> 3, q = lane & 7;
  const unsigned int* recw = (const unsigned int*)rec;
  float acc[4][4];
#pragma unroll
  for (int h = 0; h < 4; ++h)
#pragma unroll
    for (int j = 0; j < 4; ++j) acc[h][j] = 0.f;
  for (int p = p0 + g; p < p1; p += 8) {
    int s = (int)(recw[p * 2] >> 3);
    float4 a = ((const float4*)att4)[p];
    ushort4 ev = *(const ushort4*)(E1bf + s * 32 + q * 4);
    float e0 = bf2f(ev.x), e1 = bf2f(ev.y), e2 = bf2f(ev.z), e3 = bf2f(ev.w);
    acc[0][0] += a.x * e0; acc[0][1] += a.x * e1; acc[0][2] += a.x * e2; acc[0][3] += a.x * e3;
    acc[1][0] += a.y * e0; acc[1][1] += a.y * e1; acc[1][2] += a.y * e2; acc[1][3] += a.y * e3;
    acc[2][0] += a.z * e0; acc[2][1] += a.z * e1; acc[2][2] += a.z * e2; acc[2][3] += a.z * e3;
    acc[3][0] += a.w * e0; acc[3][1] += a.w * e1; acc[3][2] += a.w * e2; acc[3][3] += a.w * e3;
  }
#pragma unroll
  for (int h = 0; h < 4; ++h)
#pragma unroll
    for (int j = 0; j < 4; ++j) {
      acc[h][j] += __shfl_xor(acc[h][j], 8);
      acc[h][j] += __shfl_xor(acc[h][j], 16);
      acc[h][j] += __shfl_xor(acc[h][j], 32);
    }
  if (lane < 8) {
    float4 zi = *(const float4*)(zinv4 + n * 4);
#pragma unroll
    for (int j = 0; j < 4; ++j) {
      acc[0][j] *= zi.x; acc[1][j] *= zi.y; acc[2][j] *= zi.z; acc[3][j] *= zi.w;
    }
    float4 e1v = *(const float4*)(ego1 + n * 32 + q * 4);
#pragma unroll
    for (int h = 0; h < 4; ++h) {
      float4 v1, v2;
      v1.x = e1v.x + acc[h][0]; v2.x = e1v.x * acc[h][0];
      v1.y = e1v.y + acc[h][1]; v2.y = e1v.y * acc[h][1];
      v1.z = e1v.z + acc[h][2]; v2.z = e1v.z * acc[h][2];
      v1.w = e1v.w + acc[h][3]; v2.w = e1v.w * acc[h][3];
      *(float4*)&s1[wv][h][q * 4] = v1;
      *(float4*)&s2[wv][h][q * 4] = v2;
    }
  }
  __syncthreads();
  if (lane < 32) {
    int h = (lane >> 2) & 3, j = lane & 3;
    const float* sp = (lane < 16) ? &s1[wv][h][0] : &s2[wv][h][0];
    const float* wp = (lane < 16) ? &wt1[j][0] : &wt2[j][0];
    float o = 0.f;
#pragma unroll
    for (int dd = 0; dd < 32; dd += 4) {
      float4 sv = *(const float4*)(sp + dd);
      float4 wv4 = *(const float4*)(wp + dd);
      o += sv.x * wv4.x + sv.y * wv4.y + sv.z * wv4.z + sv.w * wv4.w;
    }
    o += (lane < 16) ? bb[j] : bb[4 + j];
    o = (o >= 0.f) ? o : 0.01f * o;
    float other = __shfl_xor(o, 16);
    if (lane < 16) ego2[n * 16 + h * 4 + j] = o + other;
  }
}

// ---------------- gather user/item rows with l2norm into U, V ----------------
__global__ void k_uv(const float* __restrict__ E, const float* __restrict__ E1,
                     const float* __restrict__ E2, const int* __restrict__ uid,
                     const int* __restrict__ iid, float* __restrict__ U,
                     float* __restrict__ V) {
  int row = (blockIdx.x * 256 + threadIdx.x) >> 6;
  int lane = threadIdx.x & 63;
  if (row >= 1000 + 4096) return;
  int id = (row < 1000) ? uid[row] : iid[row - 1000];
  float* dest = (row < 1000) ? (U + row * 112) : (V + (row - 1000) * 112);
  float v1 = (lane < 32) ? E1[id * 32 + lane] : 0.f;
  float s1 = v1 * v1;
  for (int m = 1; m < 64; m <<= 1) s1 += __shfl_xor(s1, m);
  float v2 = (lane < 16) ? E2[id * 16 + lane] : 0.f;
  float s2 = v2 * v2;
  for (int m = 1; m < 64; m <<= 1) s2 += __shfl_xor(s2, m);
  float i1 = 1.f / fmaxf(sqrtf(s1), 1e-12f);
  float i2 = 1.f / fmaxf(sqrtf(s2), 1e-12f);
  dest[lane] = E[id * 64 + lane];
  if (lane < 32) dest[64 + lane] = v1 * i1;
  if (lane < 16) dest[96 + lane] = v2 * i2;
}

// ---------------- final small GEMM: C[1000,4096] = U @ V^T (K=112) ----------------
__global__ void k_gemm(const float* __restrict__ U, const float* __restrict__ V,
                       float* __restrict__ C) {
  __shared__ float Us[16][113], Vs[16][113];
  int tx = threadIdx.x & 15, ty = threadIdx.x >> 4;
  int u0 = blockIdx.y * 16, v0 = blockIdx.x * 16;
  for (int i = threadIdx.x; i < 16 * 112; i += 256) {
    int rr = i / 112, cc = i % 112;
    int ur = u0 + rr;
    Us[rr][cc] = (ur < 1000) ? U[ur * 112 + cc] : 0.f;
    Vs[rr][cc] = V[(v0 + rr) * 112 + cc];
  }
  __syncthreads();
  int u = u0 + ty;
  if (u >= 1000) return;
  float acc = 0.f;
#pragma unroll
  for (int k = 0; k < 112; ++k) acc += Us[ty][k] * Vs[tx][k];
  C[u * 4096 + v0 + tx] = acc;
}

extern "C" void kernel_launch(void* const* d_in, const int* in_sizes, int n_in,
                              void* d_out, int out_size, void* d_ws, size_t ws_size,
                              hipStream_t stream) {
  const int* src = (const int*)d_in[0];
  const int* dst = (const int*)d_in[1];
  const int* etype = (const int*)d_in[2];
  const int* uid = (const int*)d_in[4];
  const int* iid = (const int*)d_in[5];
  const float* entity = (const float*)d_in[6];
  const float* rel = (const float*)d_in[7];
  const float* W_R = (const float*)d_in[8];
  const float* W_A = (const float*)d_in[9];
  const float* W1_0 = (const float*)d_in[10];
  const float* b1_0 = (const float*)d_in[11];
  const float* W2_0 = (const float*)d_in[12];
  const float* b2_0 = (const float*)d_in[13];
  const float* W1_1 = (const float*)d_in[14];
  const float* b1_1 = (const float*)d_in[15];
  const float* W2_1 = (const float*)d_in[16];
  const float* b2_1 = (const float*)d_in[17];
  float* out = (float*)d_out;

  char* ws = (char*)d_ws;
  // ego1/e1bf/ego2 must NOT alias T1n/T2n (k_fused0 reads T while writing ego1).
  unsigned char*  T1n  = (unsigned char*) (ws + 0);            //  51,200,000
  unsigned char*  T2n  = (unsigned char*) (ws + 51200000);     //  51,200,000
  float*          att4 = (float*)         (ws + 102400000);    //  25,600,000 (raw e)
  uint2*          rec  = (uint2*)         (ws + 128000000);    //  12,800,000
  int*            rowp = (int*)           (ws + 140800000);    //     400,128
  int*            cnt  = (int*)           (ws + 141200128);    //     400,128
  int*            bsum = (int*)           (ws + 141600256);    //         512
  unsigned short* Wbf  = (unsigned short*)(ws + 141600768);    //      65,536
  float*          rea  = (float*)         (ws + 141666304);    //       2,048
  unsigned short* Ebf  = (unsigned short*)(ws + 141668352);    //  12,800,000
  float*          zinv4= (float*)         (ws + 154468352);    //   1,600,000
  float*          ego1 = (float*)         (ws + 156068352);    //  12,800,000
  unsigned short* e1bf = (unsigned short*)(ws + 168868352);    //   6,400,000
  float*          ego2 = (float*)         (ws + 175268352);    //   6,400,000
  float*          U    = (float*)         (ws + 181668352);    //     448,000
  float*          V    = (float*)         (ws + 182116352);    //   1,835,008
  int*            epos = (int*)           (ws + 183951360);    //   6,400,000
  // total: 190,351,360 bytes

  hipMemsetAsync(cnt, 0, NN * sizeof(int), stream);
  k_prep<<<130, 256, 0, stream>>>(W_R, W_A, rel, Wbf, rea);
  k_cvt<<<6250, 256, 0, stream>>>(entity, Ebf);
  k_proj<<<(NN + 63) / 64, 256, 0, stream>>>(Ebf, Wbf, rea, T1n, T2n);
  k_hist<<<NE / 256, 256, 0, stream>>>(dst, cnt, epos);
  k_scan1<<<NSCAN, SCAN_B, 0, stream>>>(cnt, rowp, bsum);
  k_scan2<<<1, 64, 0, stream>>>(bsum);
  k_scan3<<<NSCAN, SCAN_B, 0, stream>>>(rowp, bsum);
  k_scatter<<<NE / 256, 256, 0, stream>>>(src, dst, etype, rowp, epos, rec);
  k_fused0<<<NN / 4, 256, 0, stream>>>(entity, Ebf, T1n, T2n, rec, rowp,
                                       att4, zinv4, W1_0, b1_0, W2_0, b2_0,
                                       ego1, e1bf);
  k_fused1<<<NN / 4, 256, 0, stream>>>(ego1, e1bf, att4, zinv4, rec, rowp,
                                       W1_1, b1_1, W2_1, b2_1, ego2);
  k_uv<<<(1000 + 4096 + 3) / 4, 256, 0, stream>>>(entity, ego1, ego2, uid, iid, U, V);
  k_gemm<<<dim3(4096 / 16, (1000 + 15) / 16), 256, 0, stream>>>(U, V, out);
}

// Round 14
// 496.788 us; speedup vs baseline: 1.2980x; 1.0134x over previous
//
#include <hip/hip_runtime.h>
#include <hip/hip_bf16.h>
#include <math.h>

#define NN 100000
#define NR 8
#define NE 1600000
// ED=RD=64, H=4, A=16, D1=32, D2=16

typedef __attribute__((ext_vector_type(8))) short short8v;
typedef __attribute__((ext_vector_type(4))) float float4v;
typedef __attribute__((ext_vector_type(2))) float float2v;

__device__ inline float bf2f(unsigned short u) {
  union { unsigned int i; float f; } v; v.i = ((unsigned int)u) << 16; return v.f;
}
__device__ inline unsigned short f2bf(float f) {
  __hip_bfloat16 h = __float2bfloat16(f);
  return *reinterpret_cast<unsigned short*>(&h);
}
__device__ inline float fast_tanh(float x) {
  float ex = __expf(2.f * x);
  return 1.f - 2.f * __builtin_amdgcn_rcpf(ex + 1.f);
}

// ---------------- weight prep: Wbf[c][e] bf16 col-major, rea[512] ----------------
__global__ void k_prep(const float* __restrict__ W_R, const float* __restrict__ W_A,
                       const float* __restrict__ rel, unsigned short* __restrict__ Wbf,
                       float* __restrict__ r_emb_a) {
  int tid = blockIdx.x * 256 + threadIdx.x;
  if (tid < NR * 64 * 64) {
    int r = tid >> 12;
    int i = (tid >> 6) & 63;   // embed dim e
    int k = tid & 63;          // output dim within relation
    float acc = 0.f;
    const float* wr = W_R + (r * 64 + i) * 64;
    for (int j = 0; j < 64; ++j) acc += wr[j] * W_A[j * 64 + k];
    Wbf[(r * 64 + k) * 64 + i] = f2bf(acc);   // col-major: [c=r*64+k][e=i]
  } else if (tid < NR * 64 * 64 + NR * 64) {
    int idx = tid - NR * 64 * 64;
    int r = idx >> 6, k = idx & 63;
    float acc = 0.f;
    for (int j = 0; j < 64; ++j) acc += rel[r * 64 + j] * W_A[j * 64 + k];
    r_emb_a[idx] = acc;
  }
}

// ---------------- entity -> bf16 copy ----------------
__global__ void k_cvt(const float* __restrict__ E, unsigned short* __restrict__ Ebf) {
  int i = blockIdx.x * 256 + threadIdx.x;  // handles 4 floats
  float4 v = ((const float4*)E)[i];
  ushort4 o;
  o.x = f2bf(v.x); o.y = f2bf(v.y); o.z = f2bf(v.z); o.w = f2bf(v.w);
  ((ushort4*)Ebf)[i] = o;
}

// ---------------- proj via MFMA, node-major fp8 output with packed dword stores ---
__global__ void k_proj(const unsigned short* __restrict__ Ebf,
                       const unsigned short* __restrict__ Wbf,
                       const float* __restrict__ rea,
                       unsigned char* __restrict__ T1n, unsigned char* __restrict__ T2n) {
  int wv = threadIdx.x >> 6, lane = threadIdx.x & 63;
  int n0 = blockIdx.x * 64 + wv * 16;
  int mrow = lane & 15, kg = lane >> 4;  // kg in 0..3
  int node = n0 + mrow;
  int nodeC = (node < NN) ? node : NN - 1;
  bool ok = (node < NN);
  const short8v b0 = *(const short8v*)(Ebf + (long)nodeC * 64 + kg * 8);
  const short8v b1 = *(const short8v*)(Ebf + (long)nodeC * 64 + 32 + kg * 8);
  for (int ct = 0; ct < 32; ++ct) {
    int ca = ct * 16 + mrow;  // A-row (c) this lane loads
    const short8v a0 = *(const short8v*)(Wbf + ca * 64 + kg * 8);
    const short8v a1 = *(const short8v*)(Wbf + ca * 64 + 32 + kg * 8);
    float4v acc = {0.f, 0.f, 0.f, 0.f};
    acc = __builtin_amdgcn_mfma_f32_16x16x32_bf16(a0, b0, acc, 0, 0, 0);
    acc = __builtin_amdgcn_mfma_f32_16x16x32_bf16(a1, b1, acc, 0, 0, 0);
    int c0 = ct * 16 + kg * 4;  // this lane's 4 consecutive output cols
    float4 rv4 = *(const float4*)(rea + c0);
    unsigned int p1 = __builtin_amdgcn_cvt_pk_fp8_f32(fast_tanh(acc[0]), fast_tanh(acc[1]), 0u, false);
    p1 = __builtin_amdgcn_cvt_pk_fp8_f32(fast_tanh(acc[2]), fast_tanh(acc[3]), p1, true);
    unsigned int p2 = __builtin_amdgcn_cvt_pk_fp8_f32(fast_tanh(acc[0] + rv4.x), fast_tanh(acc[1] + rv4.y), 0u, false);
    p2 = __builtin_amdgcn_cvt_pk_fp8_f32(fast_tanh(acc[2] + rv4.z), fast_tanh(acc[3] + rv4.w), p2, true);
    if (ok) {
      *(unsigned int*)(T1n + (long)node * 512 + c0) = p1;
      *(unsigned int*)(T2n + (long)node * 512 + c0) = p2;
    }
  }
}

// ---------------- CSR build ----------------
// hist also records each edge's position within its destination's run.
__global__ void k_hist(const int* __restrict__ dst, int* __restrict__ cnt,
                       int* __restrict__ epos) {
  int e = blockIdx.x * 256 + threadIdx.x;
  if (e < NE) epos[e] = atomicAdd(&cnt[dst[e]], 1);
}

#define SCAN_B 1024
#define NSCAN ((NN + SCAN_B - 1) / SCAN_B)  // 98

__global__ void k_scan1(const int* __restrict__ cnt, int* __restrict__ rowp,
                        int* __restrict__ bsum) {
  __shared__ int s[SCAN_B];
  int t = threadIdx.x, g = blockIdx.x * SCAN_B + t;
  s[t] = (g < NN) ? cnt[g] : 0;
  __syncthreads();
  for (int off = 1; off < SCAN_B; off <<= 1) {
    int x = (t >= off) ? s[t - off] : 0;
    __syncthreads();
    s[t] += x;
    __syncthreads();
  }
  if (g < NN) rowp[g + 1] = s[t];
  if (t == SCAN_B - 1) bsum[blockIdx.x] = s[t];
}

__global__ void k_scan2(int* bsum) {
  if (threadIdx.x == 0) {
    int acc = 0;
    for (int i = 0; i < NSCAN; ++i) { int v = bsum[i]; bsum[i] = acc; acc += v; }
  }
}

__global__ void k_scan3(int* rowp, const int* __restrict__ bsum) {
  int t = threadIdx.x, g = blockIdx.x * SCAN_B + t;
  if (g < NN) rowp[g + 1] += bsum[blockIdx.x];
  if (g == 0) rowp[0] = 0;
}

// scatter (atomic-free): p = rowp[dst] + epos; ONE packed 4-byte record per edge
__global__ void k_scatter(const int* __restrict__ src, const int* __restrict__ dst,
                          const int* __restrict__ etype, const int* __restrict__ rowp,
                          const int* __restrict__ epos, unsigned int* __restrict__ rec) {
  int e = blockIdx.x * 256 + threadIdx.x;
  if (e >= NE) return;
  int d = dst[e];
  int p = rowp[d] + epos[e];
  rec[p] = ((unsigned int)src[e] << 3) | (unsigned int)etype[e];
}

// ---------------- fused attention + max-free softmax + message + transform, L0 ----
// wave per node; 4 edges/iter; 16 lanes/edge. Lane (g=lane>>4 edge-slot, q=lane&15).
// Lane's T-slice bytes q*4..q*4+3 lie in head q>>2. |per-head logit| <= 16 so
// exp() without max subtraction is safe (softmax is shift-invariant).
__global__ void k_fused0(const float* __restrict__ E, const unsigned short* __restrict__ Ebf,
                         const unsigned char* __restrict__ T1n,
                         const unsigned char* __restrict__ T2n,
                         const unsigned int* __restrict__ rec, const int* __restrict__ rowp,
                         unsigned short* __restrict__ att2, float* __restrict__ zinv4,
                         const float* __restrict__ W1, const float* __restrict__ b1,
                         const float* __restrict__ W2, const float* __restrict__ b2,
                         float* __restrict__ ego1, unsigned short* __restrict__ ego1bf) {
  __shared__ float wt1[8][68], wt2[8][68];  // transposed weights [j][d]
  __shared__ float bb[16];
  __shared__ float s1[4][4][68], s2[4][4][68];
  int t = threadIdx.x;
  for (int i = t; i < 512; i += 256) {
    int d = i >> 3, j = i & 7;
    wt1[j][d] = W1[i];
    wt2[j][d] = W2[i];
  }
  if (t < 8) bb[t] = b1[t];
  else if (t < 16) bb[t] = b2[t - 8];
  __syncthreads();
  int wv = t >> 6, lane = t & 63;
  int n = blockIdx.x * 4 + wv;
  int p0 = rowp[n], p1 = rowp[n + 1];
  int g = lane >> 4, q = lane & 15;
  int bl = (lane & 48) | (lane & 3);  // lane g*16 + (q&3): head-0 source lane
  float acc[4][4];  // [head][dim within block]
#pragma unroll
  for (int h = 0; h < 4; ++h)
#pragma unroll
    for (int j = 0; j < 4; ++j) acc[h][j] = 0.f;
  float z0 = 0.f, z1 = 0.f, z2 = 0.f, z3 = 0.f;
  for (int p = p0 + g; p < p1; p += 4) {
    unsigned int rv = rec[p];
    int s = (int)(rv >> 3), r = (int)(rv & 7);
    unsigned int aw = *(const unsigned int*)(T1n + (long)s * 512 + r * 64 + q * 4);
    unsigned int bw = *(const unsigned int*)(T2n + (long)n * 512 + r * 64 + q * 4);
    float2v fa0 = __builtin_amdgcn_cvt_pk_f32_fp8(aw, false);
    float2v fa1 = __builtin_amdgcn_cvt_pk_f32_fp8(aw, true);
    float2v fb0 = __builtin_amdgcn_cvt_pk_f32_fp8(bw, false);
    float2v fb1 = __builtin_amdgcn_cvt_pk_f32_fp8(bw, true);
    float dot = fa0.x * fb0.x + fa0.y * fb0.y + fa1.x * fb1.x + fa1.y * fb1.y;
    dot += __shfl_xor(dot, 1);
    dot += __shfl_xor(dot, 2);       // 4 lanes of head group q>>2 hold logit
    float e = __expf(dot);           // max-free: |logit| <= 16
    float e0 = __shfl(e, bl);
    float e1 = __shfl(e, bl + 4);
    float e2 = __shfl(e, bl + 8);
    float e3 = __shfl(e, bl + 12);
    z0 += e0; z1 += e1; z2 += e2; z3 += e3;
    if (q == 0) {
      ushort4 av;
      av.x = f2bf(e0); av.y = f2bf(e1); av.z = f2bf(e2); av.w = f2bf(e3);
      ((ushort4*)att2)[p] = av;
    }
    ushort4 ev = *(const ushort4*)(Ebf + s * 64 + q * 4);
    float v0 = bf2f(ev.x), v1 = bf2f(ev.y), v2 = bf2f(ev.z), v3 = bf2f(ev.w);
    acc[0][0] += e0 * v0; acc[0][1] += e0 * v1; acc[0][2] += e0 * v2; acc[0][3] += e0 * v3;
    acc[1][0] += e1 * v0; acc[1][1] += e1 * v1; acc[1][2] += e1 * v2; acc[1][3] += e1 * v3;
    acc[2][0] += e2 * v0; acc[2][1] += e2 * v1; acc[2][2] += e2 * v2; acc[2][3] += e2 * v3;
    acc[3][0] += e3 * v0; acc[3][1] += e3 * v1; acc[3][2] += e3 * v2; acc[3][3] += e3 * v3;
  }
#pragma unroll
  for (int h = 0; h < 4; ++h)
#pragma unroll
    for (int j = 0; j < 4; ++j) {
      acc[h][j] += __shfl_xor(acc[h][j], 16);
      acc[h][j] += __shfl_xor(acc[h][j], 32);
    }
  z0 += __shfl_xor(z0, 16); z0 += __shfl_xor(z0, 32);
  z1 += __shfl_xor(z1, 16); z1 += __shfl_xor(z1, 32);
  z2 += __shfl_xor(z2, 16); z2 += __shfl_xor(z2, 32);
  z3 += __shfl_xor(z3, 16); z3 += __shfl_xor(z3, 32);
  float zi0 = 1.f / fmaxf(z0, 1e-12f);
  float zi1 = 1.f / fmaxf(z1, 1e-12f);
  float zi2 = 1.f / fmaxf(z2, 1e-12f);
  float zi3 = 1.f / fmaxf(z3, 1e-12f);
  if (lane == 0) *(float4*)(zinv4 + n * 4) = make_float4(zi0, zi1, zi2, zi3);
  if (lane < 16) {
    acc[0][0] *= zi0; acc[0][1] *= zi0; acc[0][2] *= zi0; acc[0][3] *= zi0;
    acc[1][0] *= zi1; acc[1][1] *= zi1; acc[1][2] *= zi1; acc[1][3] *= zi1;
    acc[2][0] *= zi2; acc[2][1] *= zi2; acc[2][2] *= zi2; acc[2][3] *= zi2;
    acc[3][0] *= zi3; acc[3][1] *= zi3; acc[3][2] *= zi3; acc[3][3] *= zi3;
    float4 edv = *(const float4*)(E + n * 64 + q * 4);
#pragma unroll
    for (int h = 0; h < 4; ++h) {
      float4 v1v, v2v;
      v1v.x = edv.x + acc[h][0]; v2v.x = edv.x * acc[h][0];
      v1v.y = edv.y + acc[h][1]; v2v.y = edv.y * acc[h][1];
      v1v.z = edv.z + acc[h][2]; v2v.z = edv.z * acc[h][2];
      v1v.w = edv.w + acc[h][3]; v2v.w = edv.w * acc[h][3];
      *(float4*)&s1[wv][h][q * 4] = v1v;
      *(float4*)&s2[wv][h][q * 4] = v2v;
    }
  }
  __syncthreads();
  int h = (lane >> 3) & 3, j = lane & 7;
  const float* sp = (lane < 32) ? &s1[wv][h][0] : &s2[wv][h][0];
  const float* wp = (lane < 32) ? &wt1[j][0] : &wt2[j][0];
  float o = 0.f;
#pragma unroll
  for (int d = 0; d < 64; d += 4) {
    float4 sv = *(const float4*)(sp + d);
    float4 wv4 = *(const float4*)(wp + d);
    o += sv.x * wv4.x + sv.y * wv4.y + sv.z * wv4.z + sv.w * wv4.w;
  }
  o += (lane < 32) ? bb[j] : bb[8 + j];
  o = (o >= 0.f) ? o : 0.01f * o;
  float other = __shfl_xor(o, 32);
  if (lane < 32) {
    float r = o + other;
    ego1[n * 32 + h * 8 + j] = r;
    ego1bf[n * 32 + h * 8 + j] = f2bf(r);
  }
}

// ---------------- fused message + bi-transform, layer 1 ----------------
// wave per node; 8 edges/iter; bf16 raw e from att2, per-node zinv applied post-reduce.
__global__ void k_fused1(const float* __restrict__ ego1, const unsigned short* __restrict__ E1bf,
                         const unsigned short* __restrict__ att2, const float* __restrict__ zinv4,
                         const unsigned int* __restrict__ rec, const int* __restrict__ rowp,
                         const float* __restrict__ W1, const float* __restrict__ b1,
                         const float* __restrict__ W2, const float* __restrict__ b2,
                         float* __restrict__ ego2) {
  __shared__ float wt1[4][36], wt2[4][36], bb[8];
  __shared__ float s1[4][4][36], s2[4][4][36];
  int t = threadIdx.x;
  if (t < 128) { int d = t >> 2, j = t & 3; wt1[j][d] = W1[t]; wt2[j][d] = W2[t]; }
  if (t < 4) bb[t] = b1[t];
  else if (t < 8) bb[t] = b2[t - 4];
  __syncthreads();
  int wv = t >> 6, lane = t & 63;
  int n = blockIdx.x * 4 + wv;
  int p0 = rowp[n], p1 = rowp[n + 1];
  int g = lane >> 3, q = lane & 7;
  float acc[4][4];
#pragma unroll
  for (int h = 0; h < 4; ++h)
#pragma unroll
    for (int j = 0; j < 4; ++j) acc[h][j] = 0.f;
  for (int p = p0 + g; p < p1; p += 8) {
    int s = (int)(rec[p] >> 3);
    ushort4 av = ((const ushort4*)att2)[p];
    float ax = bf2f(av.x), ay = bf2f(av.y), az = bf2f(av.z), aw = bf2f(av.w);
    ushort4 ev = *(const ushort4*)(E1bf + s * 32 + q * 4);
    float e0 = bf2f(ev.x), e1 = bf2f(ev.y), e2 = bf2f(ev.z), e3 = bf2f(ev.w);
    acc[0][0] += ax * e0; acc[0][1] += ax * e1; acc[0][2] += ax * e2; acc[0][3] += ax * e3;
    acc[1][0] += ay * e0; acc[1][1] += ay * e1; acc[1][2] += ay * e2; acc[1][3] += ay * e3;
    acc[2][0] += az * e0; acc[2][1] += az * e1; acc[2][2] += az * e2; acc[2][3] += az * e3;
    acc[3][0] += aw * e0; acc[3][1] += aw * e1; acc[3][2] += aw * e2; acc[3][3] += aw * e3;
  }
#pragma unroll
  for (int h = 0; h < 4; ++h)
#pragma unroll
    for (int j = 0; j < 4; ++j) {
      acc[h][j] += __shfl_xor(acc[h][j], 8);
      acc[h][j] += __shfl_xor(acc[h][j], 16);
      acc[h][j] += __shfl_xor(acc[h][j], 32);
    }
  if (lane < 8) {
    float4 zi = *(const float4*)(zinv4 + n * 4);
#pragma unroll
    for (int j = 0; j < 4; ++j) {
      acc[0][j] *= zi.x; acc[1][j] *= zi.y; acc[2][j] *= zi.z; acc[3][j] *= zi.w;
    }
    float4 e1v = *(const float4*)(ego1 + n * 32 + q * 4);
#pragma unroll
    for (int h = 0; h < 4; ++h) {
      float4 v1, v2;
      v1.x = e1v.x + acc[h][0]; v2.x = e1v.x * acc[h][0];
      v1.y = e1v.y + acc[h][1]; v2.y = e1v.y * acc[h][1];
      v1.z = e1v.z + acc[h][2]; v2.z = e1v.z * acc[h][2];
      v1.w = e1v.w + acc[h][3]; v2.w = e1v.w * acc[h][3];
      *(float4*)&s1[wv][h][q * 4] = v1;
      *(float4*)&s2[wv][h][q * 4] = v2;
    }
  }
  __syncthreads();
  if (lane < 32) {
    int h = (lane >> 2) & 3, j = lane & 3;
    const float* sp = (lane < 16) ? &s1[wv][h][0] : &s2[wv][h][0];
    const float* wp = (lane < 16) ? &wt1[j][0] : &wt2[j][0];
    float o = 0.f;
#pragma unroll
    for (int dd = 0; dd < 32; dd += 4) {
      float4 sv = *(const float4*)(sp + dd);
      float4 wv4 = *(const float4*)(wp + dd);
      o += sv.x * wv4.x + sv.y * wv4.y + sv.z * wv4.z + sv.w * wv4.w;
    }
    o += (lane < 16) ? bb[j] : bb[4 + j];
    o = (o >= 0.f) ? o : 0.01f * o;
    float other = __shfl_xor(o, 16);
    if (lane < 16) ego2[n * 16 + h * 4 + j] = o + other;
  }
}

// ---------------- gather user/item rows with l2norm into U, V ----------------
__global__ void k_uv(const float* __restrict__ E, const float* __restrict__ E1,
                     const float* __restrict__ E2, const int* __restrict__ uid,
                     const int* __restrict__ iid, float* __restrict__ U,
                     float* __restrict__ V) {
  int row = (blockIdx.x * 256 + threadIdx.x) >> 6;
  int lane = threadIdx.x & 63;
  if (row >= 1000 + 4096) return;
  int id = (row < 1000) ? uid[row] : iid[row - 1000];
  float* dest = (row < 1000) ? (U + row * 112) : (V + (row - 1000) * 112);
  float v1 = (lane < 32) ? E1[id * 32 + lane] : 0.f;
  float s1 = v1 * v1;
  for (int m = 1; m < 64; m <<= 1) s1 += __shfl_xor(s1, m);
  float v2 = (lane < 16) ? E2[id * 16 + lane] : 0.f;
  float s2 = v2 * v2;
  for (int m = 1; m < 64; m <<= 1) s2 += __shfl_xor(s2, m);
  float i1 = 1.f / fmaxf(sqrtf(s1), 1e-12f);
  float i2 = 1.f / fmaxf(sqrtf(s2), 1e-12f);
  dest[lane] = E[id * 64 + lane];
  if (lane < 32) dest[64 + lane] = v1 * i1;
  if (lane < 16) dest[96 + lane] = v2 * i2;
}

// ---------------- final small GEMM: C[1000,4096] = U @ V^T (K=112) ----------------
__global__ void k_gemm(const float* __restrict__ U, const float* __restrict__ V,
                       float* __restrict__ C) {
  __shared__ float Us[16][113], Vs[16][113];
  int tx = threadIdx.x & 15, ty = threadIdx.x >> 4;
  int u0 = blockIdx.y * 16, v0 = blockIdx.x * 16;
  for (int i = threadIdx.x; i < 16 * 112; i += 256) {
    int rr = i / 112, cc = i % 112;
    int ur = u0 + rr;
    Us[rr][cc] = (ur < 1000) ? U[ur * 112 + cc] : 0.f;
    Vs[rr][cc] = V[(v0 + rr) * 112 + cc];
  }
  __syncthreads();
  int u = u0 + ty;
  if (u >= 1000) return;
  float acc = 0.f;
#pragma unroll
  for (int k = 0; k < 112; ++k) acc += Us[ty][k] * Vs[tx][k];
  C[u * 4096 + v0 + tx] = acc;
}

extern "C" void kernel_launch(void* const* d_in, const int* in_sizes, int n_in,
                              void* d_out, int out_size, void* d_ws, size_t ws_size,
                              hipStream_t stream) {
  const int* src = (const int*)d_in[0];
  const int* dst = (const int*)d_in[1];
  const int* etype = (const int*)d_in[2];
  const int* uid = (const int*)d_in[4];
  const int* iid = (const int*)d_in[5];
  const float* entity = (const float*)d_in[6];
  const float* rel = (const float*)d_in[7];
  const float* W_R = (const float*)d_in[8];
  const float* W_A = (const float*)d_in[9];
  const float* W1_0 = (const float*)d_in[10];
  const float* b1_0 = (const float*)d_in[11];
  const float* W2_0 = (const float*)d_in[12];
  const float* b2_0 = (const float*)d_in[13];
  const float* W1_1 = (const float*)d_in[14];
  const float* b1_1 = (const float*)d_in[15];
  const float* W2_1 = (const float*)d_in[16];
  const float* b2_1 = (const float*)d_in[17];
  float* out = (float*)d_out;

  char* ws = (char*)d_ws;
  // ego1/e1bf/ego2 must NOT alias T1n/T2n (k_fused0 reads T while writing ego1).
  unsigned char*  T1n  = (unsigned char*) (ws + 0);            //  51,200,000
  unsigned char*  T2n  = (unsigned char*) (ws + 51200000);     //  51,200,000
  unsigned short* att2 = (unsigned short*)(ws + 102400000);    //  12,800,000 (raw e, bf16)
  unsigned int*   rec  = (unsigned int*)  (ws + 115200000);    //   6,400,000
  int*            rowp = (int*)           (ws + 121600000);    //     400,128
  int*            cnt  = (int*)           (ws + 122000128);    //     400,128
  int*            bsum = (int*)           (ws + 122400256);    //         512
  unsigned short* Wbf  = (unsigned short*)(ws + 122400768);    //      65,536
  float*          rea  = (float*)         (ws + 122466304);    //       2,048
  unsigned short* Ebf  = (unsigned short*)(ws + 122468352);    //  12,800,000
  float*          zinv4= (float*)         (ws + 135268352);    //   1,600,000
  float*          ego1 = (float*)         (ws + 136868352);    //  12,800,000
  unsigned short* e1bf = (unsigned short*)(ws + 149668352);    //   6,400,000
  float*          ego2 = (float*)         (ws + 156068352);    //   6,400,000
  float*          U    = (float*)         (ws + 162468352);    //     448,000
  float*          V    = (float*)         (ws + 162916352);    //   1,835,008
  int*            epos = (int*)           (ws + 164751360);    //   6,400,000
  // total: 171,151,360 bytes

  hipMemsetAsync(cnt, 0, NN * sizeof(int), stream);
  k_prep<<<130, 256, 0, stream>>>(W_R, W_A, rel, Wbf, rea);
  k_cvt<<<6250, 256, 0, stream>>>(entity, Ebf);
  k_proj<<<(NN + 63) / 64, 256, 0, stream>>>(Ebf, Wbf, rea, T1n, T2n);
  k_hist<<<NE / 256, 256, 0, stream>>>(dst, cnt, epos);
  k_scan1<<<NSCAN, SCAN_B, 0, stream>>>(cnt, rowp, bsum);
  k_scan2<<<1, 64, 0, stream>>>(bsum);
  k_scan3<<<NSCAN, SCAN_B, 0, stream>>>(rowp, bsum);
  k_scatter<<<NE / 256, 256, 0, stream>>>(src, dst, etype, rowp, epos, rec);
  k_fused0<<<NN / 4, 256, 0, stream>>>(entity, Ebf, T1n, T2n, rec, rowp,
                                       att2, zinv4, W1_0, b1_0, W2_0, b2_0,
                                       ego1, e1bf);
  k_fused1<<<NN / 4, 256, 0, stream>>>(ego1, e1bf, att2, zinv4, rec, rowp,
                                       W1_1, b1_1, W2_1, b2_1, ego2);
  k_uv<<<(1000 + 4096 + 3) / 4, 256, 0, stream>>>(entity, ego1, ego2, uid, iid, U, V);
  k_gemm<<<dim3(4096 / 16, (1000 + 15) / 16), 256, 0, stream>>>(U, V, out);
}

// Round 15
// 496.030 us; speedup vs baseline: 1.3000x; 1.0015x over previous
//
#include <hip/hip_runtime.h>
#include <hip/hip_bf16.h>
#include <math.h>

#define NN 100000
#define NR 8
#define NE 1600000
// ED=RD=64, H=4, A=16, D1=32, D2=16

typedef __attribute__((ext_vector_type(8))) short short8v;
typedef __attribute__((ext_vector_type(4))) float float4v;
typedef __attribute__((ext_vector_type(2))) float float2v;

__device__ inline float bf2f(unsigned short u) {
  union { unsigned int i; float f; } v; v.i = ((unsigned int)u) << 16; return v.f;
}
__device__ inline unsigned short f2bf(float f) {
  __hip_bfloat16 h = __float2bfloat16(f);
  return *reinterpret_cast<unsigned short*>(&h);
}
__device__ inline float fast_tanh(float x) {
  float ex = __expf(2.f * x);
  return 1.f - 2.f * __builtin_amdgcn_rcpf(ex + 1.f);
}

// ---------------- weight prep: Wbf[c][e] bf16 col-major, rea[512] ----------------
__global__ void k_prep(const float* __restrict__ W_R, const float* __restrict__ W_A,
                       const float* __restrict__ rel, unsigned short* __restrict__ Wbf,
                       float* __restrict__ r_emb_a) {
  int tid = blockIdx.x * 256 + threadIdx.x;
  if (tid < NR * 64 * 64) {
    int r = tid >> 12;
    int i = (tid >> 6) & 63;   // embed dim e
    int k = tid & 63;          // output dim within relation
    float acc = 0.f;
    const float* wr = W_R + (r * 64 + i) * 64;
    for (int j = 0; j < 64; ++j) acc += wr[j] * W_A[j * 64 + k];
    Wbf[(r * 64 + k) * 64 + i] = f2bf(acc);   // col-major: [c=r*64+k][e=i]
  } else if (tid < NR * 64 * 64 + NR * 64) {
    int idx = tid - NR * 64 * 64;
    int r = idx >> 6, k = idx & 63;
    float acc = 0.f;
    for (int j = 0; j < 64; ++j) acc += rel[r * 64 + j] * W_A[j * 64 + k];
    r_emb_a[idx] = acc;
  }
}

// ---------------- entity -> bf16 copy ----------------
__global__ void k_cvt(const float* __restrict__ E, unsigned short* __restrict__ Ebf) {
  int i = blockIdx.x * 256 + threadIdx.x;  // handles 4 floats
  float4 v = ((const float4*)E)[i];
  ushort4 o;
  o.x = f2bf(v.x); o.y = f2bf(v.y); o.z = f2bf(v.z); o.w = f2bf(v.w);
  ((ushort4*)Ebf)[i] = o;
}

// ---------------- proj via MFMA, node-major fp8 output with packed dword stores ---
__global__ void k_proj(const unsigned short* __restrict__ Ebf,
                       const unsigned short* __restrict__ Wbf,
                       const float* __restrict__ rea,
                       unsigned char* __restrict__ T1n, unsigned char* __restrict__ T2n) {
  int wv = threadIdx.x >> 6, lane = threadIdx.x & 63;
  int n0 = blockIdx.x * 64 + wv * 16;
  int mrow = lane & 15, kg = lane >> 4;  // kg in 0..3
  int node = n0 + mrow;
  int nodeC = (node < NN) ? node : NN - 1;
  bool ok = (node < NN);
  const short8v b0 = *(const short8v*)(Ebf + (long)nodeC * 64 + kg * 8);
  const short8v b1 = *(const short8v*)(Ebf + (long)nodeC * 64 + 32 + kg * 8);
  for (int ct = 0; ct < 32; ++ct) {
    int ca = ct * 16 + mrow;  // A-row (c) this lane loads
    const short8v a0 = *(const short8v*)(Wbf + ca * 64 + kg * 8);
    const short8v a1 = *(const short8v*)(Wbf + ca * 64 + 32 + kg * 8);
    float4v acc = {0.f, 0.f, 0.f, 0.f};
    acc = __builtin_amdgcn_mfma_f32_16x16x32_bf16(a0, b0, acc, 0, 0, 0);
    acc = __builtin_amdgcn_mfma_f32_16x16x32_bf16(a1, b1, acc, 0, 0, 0);
    int c0 = ct * 16 + kg * 4;  // this lane's 4 consecutive output cols
    float4 rv4 = *(const float4*)(rea + c0);
    unsigned int p1 = __builtin_amdgcn_cvt_pk_fp8_f32(fast_tanh(acc[0]), fast_tanh(acc[1]), 0u, false);
    p1 = __builtin_amdgcn_cvt_pk_fp8_f32(fast_tanh(acc[2]), fast_tanh(acc[3]), p1, true);
    unsigned int p2 = __builtin_amdgcn_cvt_pk_fp8_f32(fast_tanh(acc[0] + rv4.x), fast_tanh(acc[1] + rv4.y), 0u, false);
    p2 = __builtin_amdgcn_cvt_pk_fp8_f32(fast_tanh(acc[2] + rv4.z), fast_tanh(acc[3] + rv4.w), p2, true);
    if (ok) {
      *(unsigned int*)(T1n + (long)node * 512 + c0) = p1;
      *(unsigned int*)(T2n + (long)node * 512 + c0) = p2;
    }
  }
}

// ---------------- CSR build ----------------
// hist also records each edge's position within its destination's run.
__global__ void k_hist(const int* __restrict__ dst, int* __restrict__ cnt,
                       int* __restrict__ epos) {
  int e = blockIdx.x * 256 + threadIdx.x;
  if (e < NE) epos[e] = atomicAdd(&cnt[dst[e]], 1);
}

#define SCAN_B 1024
#define NSCAN ((NN + SCAN_B - 1) / SCAN_B)  // 98

__global__ void k_scan1(const int* __restrict__ cnt, int* __restrict__ rowp,
                        int* __restrict__ bsum) {
  __shared__ int s[SCAN_B];
  int t = threadIdx.x, g = blockIdx.x * SCAN_B + t;
  s[t] = (g < NN) ? cnt[g] : 0;
  __syncthreads();
  for (int off = 1; off < SCAN_B; off <<= 1) {
    int x = (t >= off) ? s[t - off] : 0;
    __syncthreads();
    s[t] += x;
    __syncthreads();
  }
  if (g < NN) rowp[g + 1] = s[t];
  if (t == SCAN_B - 1) bsum[blockIdx.x] = s[t];
}

__global__ void k_scan2(int* bsum) {
  if (threadIdx.x == 0) {
    int acc = 0;
    for (int i = 0; i < NSCAN; ++i) { int v = bsum[i]; bsum[i] = acc; acc += v; }
  }
}

__global__ void k_scan3(int* rowp, const int* __restrict__ bsum) {
  int t = threadIdx.x, g = blockIdx.x * SCAN_B + t;
  if (g < NN) rowp[g + 1] += bsum[blockIdx.x];
  if (g == 0) rowp[0] = 0;
}

// scatter (atomic-free): p = rowp[dst] + epos; ONE packed 4-byte record per edge
__global__ void k_scatter(const int* __restrict__ src, const int* __restrict__ dst,
                          const int* __restrict__ etype, const int* __restrict__ rowp,
                          const int* __restrict__ epos, unsigned int* __restrict__ rec) {
  int e = blockIdx.x * 256 + threadIdx.x;
  if (e >= NE) return;
  int d = dst[e];
  int p = rowp[d] + epos[e];
  rec[p] = ((unsigned int)src[e] << 3) | (unsigned int)etype[e];
}

// ---------------- fused attention + max-free softmax + message + transform, L0 ----
// wave per node; 4 edges/iter; 16 lanes/edge. Lane (g=lane>>4 edge-slot, q=lane&15).
// Packed float2 accumulation (v_pk_* ops) in the message MLP.
__global__ void k_fused0(const float* __restrict__ E, const unsigned short* __restrict__ Ebf,
                         const unsigned char* __restrict__ T1n,
                         const unsigned char* __restrict__ T2n,
                         const unsigned int* __restrict__ rec, const int* __restrict__ rowp,
                         unsigned short* __restrict__ att2, float* __restrict__ zinv4,
                         const float* __restrict__ W1, const float* __restrict__ b1,
                         const float* __restrict__ W2, const float* __restrict__ b2,
                         float* __restrict__ ego1, unsigned short* __restrict__ ego1bf) {
  __shared__ float wt1[8][68], wt2[8][68];  // transposed weights [j][d]
  __shared__ float bb[16];
  __shared__ float s1[4][4][68], s2[4][4][68];
  int t = threadIdx.x;
  for (int i = t; i < 512; i += 256) {
    int d = i >> 3, j = i & 7;
    wt1[j][d] = W1[i];
    wt2[j][d] = W2[i];
  }
  if (t < 8) bb[t] = b1[t];
  else if (t < 16) bb[t] = b2[t - 8];
  __syncthreads();
  int wv = t >> 6, lane = t & 63;
  int n = blockIdx.x * 4 + wv;
  int p0 = rowp[n], p1 = rowp[n + 1];
  int g = lane >> 4, q = lane & 15;
  int bl = (lane & 48) | (lane & 3);  // lane g*16 + (q&3): head-0 source lane
  float2v acc2[4][2];  // [head][dim-pair], packed f32
#pragma unroll
  for (int h = 0; h < 4; ++h) {
    acc2[h][0] = (float2v){0.f, 0.f};
    acc2[h][1] = (float2v){0.f, 0.f};
  }
  float z0 = 0.f, z1 = 0.f, z2 = 0.f, z3 = 0.f;
  for (int p = p0 + g; p < p1; p += 4) {
    unsigned int rv = rec[p];
    int s = (int)(rv >> 3), r = (int)(rv & 7);
    unsigned int aw = *(const unsigned int*)(T1n + (long)s * 512 + r * 64 + q * 4);
    unsigned int bw = *(const unsigned int*)(T2n + (long)n * 512 + r * 64 + q * 4);
    float2v fa0 = __builtin_amdgcn_cvt_pk_f32_fp8(aw, false);
    float2v fa1 = __builtin_amdgcn_cvt_pk_f32_fp8(aw, true);
    float2v fb0 = __builtin_amdgcn_cvt_pk_f32_fp8(bw, false);
    float2v fb1 = __builtin_amdgcn_cvt_pk_f32_fp8(bw, true);
    float2v dp = fa0 * fb0 + fa1 * fb1;   // packed
    float dot = dp.x + dp.y;
    dot += __shfl_xor(dot, 1);
    dot += __shfl_xor(dot, 2);       // 4 lanes of head group q>>2 hold logit
    float e = __expf(dot);           // max-free: |logit| <= 16
    float e0 = __shfl(e, bl);
    float e1 = __shfl(e, bl + 4);
    float e2 = __shfl(e, bl + 8);
    float e3 = __shfl(e, bl + 12);
    z0 += e0; z1 += e1; z2 += e2; z3 += e3;
    if (q == 0) {
      ushort4 av;
      av.x = f2bf(e0); av.y = f2bf(e1); av.z = f2bf(e2); av.w = f2bf(e3);
      ((ushort4*)att2)[p] = av;
    }
    ushort4 ev = *(const ushort4*)(Ebf + s * 64 + q * 4);
    float2v vlo = {bf2f(ev.x), bf2f(ev.y)};
    float2v vhi = {bf2f(ev.z), bf2f(ev.w)};
    acc2[0][0] += e0 * vlo; acc2[0][1] += e0 * vhi;
    acc2[1][0] += e1 * vlo; acc2[1][1] += e1 * vhi;
    acc2[2][0] += e2 * vlo; acc2[2][1] += e2 * vhi;
    acc2[3][0] += e3 * vlo; acc2[3][1] += e3 * vhi;
  }
  float acc[4][4];
#pragma unroll
  for (int h = 0; h < 4; ++h) {
    acc[h][0] = acc2[h][0].x; acc[h][1] = acc2[h][0].y;
    acc[h][2] = acc2[h][1].x; acc[h][3] = acc2[h][1].y;
  }
#pragma unroll
  for (int h = 0; h < 4; ++h)
#pragma unroll
    for (int j = 0; j < 4; ++j) {
      acc[h][j] += __shfl_xor(acc[h][j], 16);
      acc[h][j] += __shfl_xor(acc[h][j], 32);
    }
  z0 += __shfl_xor(z0, 16); z0 += __shfl_xor(z0, 32);
  z1 += __shfl_xor(z1, 16); z1 += __shfl_xor(z1, 32);
  z2 += __shfl_xor(z2, 16); z2 += __shfl_xor(z2, 32);
  z3 += __shfl_xor(z3, 16); z3 += __shfl_xor(z3, 32);
  float zi0 = 1.f / fmaxf(z0, 1e-12f);
  float zi1 = 1.f / fmaxf(z1, 1e-12f);
  float zi2 = 1.f / fmaxf(z2, 1e-12f);
  float zi3 = 1.f / fmaxf(z3, 1e-12f);
  if (lane == 0) *(float4*)(zinv4 + n * 4) = make_float4(zi0, zi1, zi2, zi3);
  if (lane < 16) {
    acc[0][0] *= zi0; acc[0][1] *= zi0; acc[0][2] *= zi0; acc[0][3] *= zi0;
    acc[1][0] *= zi1; acc[1][1] *= zi1; acc[1][2] *= zi1; acc[1][3] *= zi1;
    acc[2][0] *= zi2; acc[2][1] *= zi2; acc[2][2] *= zi2; acc[2][3] *= zi2;
    acc[3][0] *= zi3; acc[3][1] *= zi3; acc[3][2] *= zi3; acc[3][3] *= zi3;
    float4 edv = *(const float4*)(E + n * 64 + q * 4);
#pragma unroll
    for (int h = 0; h < 4; ++h) {
      float4 v1v, v2v;
      v1v.x = edv.x + acc[h][0]; v2v.x = edv.x * acc[h][0];
      v1v.y = edv.y + acc[h][1]; v2v.y = edv.y * acc[h][1];
      v1v.z = edv.z + acc[h][2]; v2v.z = edv.z * acc[h][2];
      v1v.w = edv.w + acc[h][3]; v2v.w = edv.w * acc[h][3];
      *(float4*)&s1[wv][h][q * 4] = v1v;
      *(float4*)&s2[wv][h][q * 4] = v2v;
    }
  }
  __syncthreads();
  int h = (lane >> 3) & 3, j = lane & 7;
  const float* sp = (lane < 32) ? &s1[wv][h][0] : &s2[wv][h][0];
  const float* wp = (lane < 32) ? &wt1[j][0] : &wt2[j][0];
  float o = 0.f;
#pragma unroll
  for (int d = 0; d < 64; d += 4) {
    float4 sv = *(const float4*)(sp + d);
    float4 wv4 = *(const float4*)(wp + d);
    o += sv.x * wv4.x + sv.y * wv4.y + sv.z * wv4.z + sv.w * wv4.w;
  }
  o += (lane < 32) ? bb[j] : bb[8 + j];
  o = (o >= 0.f) ? o : 0.01f * o;
  float other = __shfl_xor(o, 32);
  if (lane < 32) {
    float r = o + other;
    ego1[n * 32 + h * 8 + j] = r;
    ego1bf[n * 32 + h * 8 + j] = f2bf(r);
  }
}

// ---------------- fused message + bi-transform, layer 1 ----------------
// wave per node; 8 edges/iter; bf16 raw e from att2, per-node zinv applied post-reduce.
// Packed float2 accumulation.
__global__ void k_fused1(const float* __restrict__ ego1, const unsigned short* __restrict__ E1bf,
                         const unsigned short* __restrict__ att2, const float* __restrict__ zinv4,
                         const unsigned int* __restrict__ rec, const int* __restrict__ rowp,
                         const float* __restrict__ W1, const float* __restrict__ b1,
                         const float* __restrict__ W2, const float* __restrict__ b2,
                         float* __restrict__ ego2) {
  __shared__ float wt1[4][36], wt2[4][36], bb[8];
  __shared__ float s1[4][4][36], s2[4][4][36];
  int t = threadIdx.x;
  if (t < 128) { int d = t >> 2, j = t & 3; wt1[j][d] = W1[t]; wt2[j][d] = W2[t]; }
  if (t < 4) bb[t] = b1[t];
  else if (t < 8) bb[t] = b2[t - 4];
  __syncthreads();
  int wv = t >> 6, lane = t & 63;
  int n = blockIdx.x * 4 + wv;
  int p0 = rowp[n], p1 = rowp[n + 1];
  int g = lane >> 3, q = lane & 7;
  float2v acc2[4][2];
#pragma unroll
  for (int h = 0; h < 4; ++h) {
    acc2[h][0] = (float2v){0.f, 0.f};
    acc2[h][1] = (float2v){0.f, 0.f};
  }
  for (int p = p0 + g; p < p1; p += 8) {
    int s = (int)(rec[p] >> 3);
    ushort4 av = ((const ushort4*)att2)[p];
    float ax = bf2f(av.x), ay = bf2f(av.y), az = bf2f(av.z), aw = bf2f(av.w);
    ushort4 ev = *(const ushort4*)(E1bf + s * 32 + q * 4);
    float2v vlo = {bf2f(ev.x), bf2f(ev.y)};
    float2v vhi = {bf2f(ev.z), bf2f(ev.w)};
    acc2[0][0] += ax * vlo; acc2[0][1] += ax * vhi;
    acc2[1][0] += ay * vlo; acc2[1][1] += ay * vhi;
    acc2[2][0] += az * vlo; acc2[2][1] += az * vhi;
    acc2[3][0] += aw * vlo; acc2[3][1] += aw * vhi;
  }
  float acc[4][4];
#pragma unroll
  for (int h = 0; h < 4; ++h) {
    acc[h][0] = acc2[h][0].x; acc[h][1] = acc2[h][0].y;
    acc[h][2] = acc2[h][1].x; acc[h][3] = acc2[h][1].y;
  }
#pragma unroll
  for (int h = 0; h < 4; ++h)
#pragma unroll
    for (int j = 0; j < 4; ++j) {
      acc[h][j] += __shfl_xor(acc[h][j], 8);
      acc[h][j] += __shfl_xor(acc[h][j], 16);
      acc[h][j] += __shfl_xor(acc[h][j], 32);
    }
  if (lane < 8) {
    float4 zi = *(const float4*)(zinv4 + n * 4);
#pragma unroll
    for (int j = 0; j < 4; ++j) {
      acc[0][j] *= zi.x; acc[1][j] *= zi.y; acc[2][j] *= zi.z; acc[3][j] *= zi.w;
    }
    float4 e1v = *(const float4*)(ego1 + n * 32 + q * 4);
#pragma unroll
    for (int h = 0; h < 4; ++h) {
      float4 v1, v2;
      v1.x = e1v.x + acc[h][0]; v2.x = e1v.x * acc[h][0];
      v1.y = e1v.y + acc[h][1]; v2.y = e1v.y * acc[h][1];
      v1.z = e1v.z + acc[h][2]; v2.z = e1v.z * acc[h][2];
      v1.w = e1v.w + acc[h][3]; v2.w = e1v.w * acc[h][3];
      *(float4*)&s1[wv][h][q * 4] = v1;
      *(float4*)&s2[wv][h][q * 4] = v2;
    }
  }
  __syncthreads();
  if (lane < 32) {
    int h = (lane >> 2) & 3, j = lane & 3;
    const float* sp = (lane < 16) ? &s1[wv][h][0] : &s2[wv][h][0];
    const float* wp = (lane < 16) ? &wt1[j][0] : &wt2[j][0];
    float o = 0.f;
#pragma unroll
    for (int dd = 0; dd < 32; dd += 4) {
      float4 sv = *(const float4*)(sp + dd);
      float4 wv4 = *(const float4*)(wp + dd);
      o += sv.x * wv4.x + sv.y * wv4.y + sv.z * wv4.z + sv.w * wv4.w;
    }
    o += (lane < 16) ? bb[j] : bb[4 + j];
    o = (o >= 0.f) ? o : 0.01f * o;
    float other = __shfl_xor(o, 16);
    if (lane < 16) ego2[n * 16 + h * 4 + j] = o + other;
  }
}

// ---------------- gather user/item rows with l2norm into U, V ----------------
__global__ void k_uv(const float* __restrict__ E, const float* __restrict__ E1,
                     const float* __restrict__ E2, const int* __restrict__ uid,
                     const int* __restrict__ iid, float* __restrict__ U,
                     float* __restrict__ V) {
  int row = (blockIdx.x * 256 + threadIdx.x) >> 6;
  int lane = threadIdx.x & 63;
  if (row >= 1000 + 4096) return;
  int id = (row < 1000) ? uid[row] : iid[row - 1000];
  float* dest = (row < 1000) ? (U + row * 112) : (V + (row - 1000) * 112);
  float v1 = (lane < 32) ? E1[id * 32 + lane] : 0.f;
  float s1 = v1 * v1;
  for (int m = 1; m < 64; m <<= 1) s1 += __shfl_xor(s1, m);
  float v2 = (lane < 16) ? E2[id * 16 + lane] : 0.f;
  float s2 = v2 * v2;
  for (int m = 1; m < 64; m <<= 1) s2 += __shfl_xor(s2, m);
  float i1 = 1.f / fmaxf(sqrtf(s1), 1e-12f);
  float i2 = 1.f / fmaxf(sqrtf(s2), 1e-12f);
  dest[lane] = E[id * 64 + lane];
  if (lane < 32) dest[64 + lane] = v1 * i1;
  if (lane < 16) dest[96 + lane] = v2 * i2;
}

// ---------------- final small GEMM: C[1000,4096] = U @ V^T (K=112) ----------------
__global__ void k_gemm(const float* __restrict__ U, const float* __restrict__ V,
                       float* __restrict__ C) {
  __shared__ float Us[16][113], Vs[16][113];
  int tx = threadIdx.x & 15, ty = threadIdx.x >> 4;
  int u0 = blockIdx.y * 16, v0 = blockIdx.x * 16;
  for (int i = threadIdx.x; i < 16 * 112; i += 256) {
    int rr = i / 112, cc = i % 112;
    int ur = u0 + rr;
    Us[rr][cc] = (ur < 1000) ? U[ur * 112 + cc] : 0.f;
    Vs[rr][cc] = V[(v0 + rr) * 112 + cc];
  }
  __syncthreads();
  int u = u0 + ty;
  if (u >= 1000) return;
  float acc = 0.f;
#pragma unroll
  for (int k = 0; k < 112; ++k) acc += Us[ty][k] * Vs[tx][k];
  C[u * 4096 + v0 + tx] = acc;
}

extern "C" void kernel_launch(void* const* d_in, const int* in_sizes, int n_in,
                              void* d_out, int out_size, void* d_ws, size_t ws_size,
                              hipStream_t stream) {
  const int* src = (const int*)d_in[0];
  const int* dst = (const int*)d_in[1];
  const int* etype = (const int*)d_in[2];
  const int* uid = (const int*)d_in[4];
  const int* iid = (const int*)d_in[5];
  const float* entity = (const float*)d_in[6];
  const float* rel = (const float*)d_in[7];
  const float* W_R = (const float*)d_in[8];
  const float* W_A = (const float*)d_in[9];
  const float* W1_0 = (const float*)d_in[10];
  const float* b1_0 = (const float*)d_in[11];
  const float* W2_0 = (const float*)d_in[12];
  const float* b2_0 = (const float*)d_in[13];
  const float* W1_1 = (const float*)d_in[14];
  const float* b1_1 = (const float*)d_in[15];
  const float* W2_1 = (const float*)d_in[16];
  const float* b2_1 = (const float*)d_in[17];
  float* out = (float*)d_out;

  char* ws = (char*)d_ws;
  // ego1/e1bf/ego2 must NOT alias T1n/T2n (k_fused0 reads T while writing ego1).
  unsigned char*  T1n  = (unsigned char*) (ws + 0);            //  51,200,000
  unsigned char*  T2n  = (unsigned char*) (ws + 51200000);     //  51,200,000
  unsigned short* att2 = (unsigned short*)(ws + 102400000);    //  12,800,000 (raw e, bf16)
  unsigned int*   rec  = (unsigned int*)  (ws + 115200000);    //   6,400,000
  int*            rowp = (int*)           (ws + 121600000);    //     400,128
  int*            cnt  = (int*)           (ws + 122000128);    //     400,128
  int*            bsum = (int*)           (ws + 122400256);    //         512
  unsigned short* Wbf  = (unsigned short*)(ws + 122400768);    //      65,536
  float*          rea  = (float*)         (ws + 122466304);    //       2,048
  unsigned short* Ebf  = (unsigned short*)(ws + 122468352);    //  12,800,000
  float*          zinv4= (float*)         (ws + 135268352);    //   1,600,000
  float*          ego1 = (float*)         (ws + 136868352);    //  12,800,000
  unsigned short* e1bf = (unsigned short*)(ws + 149668352);    //   6,400,000
  float*          ego2 = (float*)         (ws + 156068352);    //   6,400,000
  float*          U    = (float*)         (ws + 162468352);    //     448,000
  float*          V    = (float*)         (ws + 162916352);    //   1,835,008
  int*            epos = (int*)           (ws + 164751360);    //   6,400,000
  // total: 171,151,360 bytes

  hipMemsetAsync(cnt, 0, NN * sizeof(int), stream);
  k_prep<<<130, 256, 0, stream>>>(W_R, W_A, rel, Wbf, rea);
  k_cvt<<<6250, 256, 0, stream>>>(entity, Ebf);
  k_proj<<<(NN + 63) / 64, 256, 0, stream>>>(Ebf, Wbf, rea, T1n, T2n);
  k_hist<<<NE / 256, 256, 0, stream>>>(dst, cnt, epos);
  k_scan1<<<NSCAN, SCAN_B, 0, stream>>>(cnt, rowp, bsum);
  k_scan2<<<1, 64, 0, stream>>>(bsum);
  k_scan3<<<NSCAN, SCAN_B, 0, stream>>>(rowp, bsum);
  k_scatter<<<NE / 256, 256, 0, stream>>>(src, dst, etype, rowp, epos, rec);
  k_fused0<<<NN / 4, 256, 0, stream>>>(entity, Ebf, T1n, T2n, rec, rowp,
                                       att2, zinv4, W1_0, b1_0, W2_0, b2_0,
                                       ego1, e1bf);
  k_fused1<<<NN / 4, 256, 0, stream>>>(ego1, e1bf, att2, zinv4, rec, rowp,
                                       W1_1, b1_1, W2_1, b2_1, ego2);
  k_uv<<<(1000 + 4096 + 3) / 4, 256, 0, stream>>>(entity, ego1, ego2, uid, iid, U, V);
  k_gemm<<<dim3(4096 / 16, (1000 + 15) / 16), 256, 0, stream>>>(U, V, out);
}